// Round 1
// baseline (4218.435 us; speedup 1.0000x reference)
//
#include <hip/hip_runtime.h>
#include <math.h>

#define D_MODEL 1024
#define DIN     2048      // d_inner
#define NST     16        // d_state
#define RDT     64        // dt_rank
#define KC      4         // d_conv
#define BB      2
#define SS      2048
#define NTOK    (BB*SS)   // 4096

__device__ __forceinline__ float silu_f(float v) {
    return v / (1.f + __expf(-v));
}

// mod[b,e] = sum_j silu(c[b,j]) * ada_w[e,j] + ada_b[e];  one wave per output
__global__ void k_adaln(const float* __restrict__ c, const float* __restrict__ ada_w,
                        const float* __restrict__ ada_b, float* __restrict__ mod) {
    int wid  = (blockIdx.x * blockDim.x + threadIdx.x) >> 6;
    int lane = threadIdx.x & 63;
    if (wid >= BB * 3 * D_MODEL) return;
    int b = wid / (3 * D_MODEL);
    int e = wid % (3 * D_MODEL);
    const float* crow = c + (size_t)b * 2 * D_MODEL;
    const float* wrow = ada_w + (size_t)e * 2 * D_MODEL;
    float acc = 0.f;
    for (int j = lane; j < 2 * D_MODEL; j += 64)
        acc += silu_f(crow[j]) * wrow[j];
    for (int off = 32; off > 0; off >>= 1) acc += __shfl_down(acc, off, 64);
    if (lane == 0) mod[(size_t)b * 3 * D_MODEL + e] = acc + ada_b[e];
}

// per-token LayerNorm + adaLN modulation -> xs
__global__ void k_lnmod(const float* __restrict__ x, const float* __restrict__ ln_w,
                        const float* __restrict__ ln_b, const float* __restrict__ mod,
                        float* __restrict__ xs) {
    int tok = blockIdx.x;
    int b   = tok / SS;
    const float* xrow = x + (size_t)tok * D_MODEL;
    float s1 = 0.f, s2 = 0.f;
    for (int i = threadIdx.x; i < D_MODEL; i += 256) {
        float v = xrow[i]; s1 += v; s2 += v * v;
    }
    __shared__ float red1[4], red2[4];
    for (int off = 32; off > 0; off >>= 1) {
        s1 += __shfl_down(s1, off, 64);
        s2 += __shfl_down(s2, off, 64);
    }
    int wid = threadIdx.x >> 6, lane = threadIdx.x & 63;
    if (lane == 0) { red1[wid] = s1; red2[wid] = s2; }
    __syncthreads();
    s1 = red1[0] + red1[1] + red1[2] + red1[3];
    s2 = red2[0] + red2[1] + red2[2] + red2[3];
    float mu   = s1 / D_MODEL;
    float var  = s2 / D_MODEL - mu * mu;
    float rstd = rsqrtf(var + 1e-5f);
    const float* shiftp = mod + (size_t)b * 3 * D_MODEL;
    const float* scalep = shiftp + D_MODEL;
    float* orow = xs + (size_t)tok * D_MODEL;
    for (int i = threadIdx.x; i < D_MODEL; i += 256) {
        float v = (xrow[i] - mu) * rstd * ln_w[i] + ln_b[i];
        orow[i] = v * (1.f + scalep[i]) + shiftp[i];
    }
}

// C[M,N] = A[M,K] (row stride lda) @ W[N,K]^T ; 64x64 tile, BK=16, 256 thr, 4x4/thr
__global__ void k_gemm(const float* __restrict__ A, int lda,
                       const float* __restrict__ W,
                       float* __restrict__ C, int ldc,
                       int M, int N, int K) {
    __shared__ float As[16][68];
    __shared__ float Ws[16][68];
    int t = threadIdx.x;
    int row0 = blockIdx.y * 64;
    int col0 = blockIdx.x * 64;
    int lr = t >> 2;          // 0..63
    int lk = (t & 3) * 4;     // 0,4,8,12
    int ty = t >> 4, tx = t & 15;
    float acc[4][4] = {};
    for (int k0 = 0; k0 < K; k0 += 16) {
        const float* ap = A + (size_t)(row0 + lr) * lda + k0 + lk;
        float a0 = ap[0], a1 = ap[1], a2 = ap[2], a3 = ap[3];
        int wn = col0 + lr;
        float b0 = 0.f, b1 = 0.f, b2 = 0.f, b3 = 0.f;
        if (wn < N) {
            const float* wp = W + (size_t)wn * K + k0 + lk;
            b0 = wp[0]; b1 = wp[1]; b2 = wp[2]; b3 = wp[3];
        }
        __syncthreads();
        As[lk + 0][lr] = a0; As[lk + 1][lr] = a1; As[lk + 2][lr] = a2; As[lk + 3][lr] = a3;
        Ws[lk + 0][lr] = b0; Ws[lk + 1][lr] = b1; Ws[lk + 2][lr] = b2; Ws[lk + 3][lr] = b3;
        __syncthreads();
        #pragma unroll
        for (int kk = 0; kk < 16; kk++) {
            float av[4], bv[4];
            #pragma unroll
            for (int i = 0; i < 4; i++) av[i] = As[kk][ty * 4 + i];
            #pragma unroll
            for (int j = 0; j < 4; j++) bv[j] = Ws[kk][tx * 4 + j];
            #pragma unroll
            for (int i = 0; i < 4; i++)
                #pragma unroll
                for (int j = 0; j < 4; j++)
                    acc[i][j] += av[i] * bv[j];
        }
    }
    #pragma unroll
    for (int i = 0; i < 4; i++) {
        int r = row0 + ty * 4 + i;
        #pragma unroll
        for (int j = 0; j < 4; j++) {
            int cc = col0 + tx * 4 + j;
            if (cc < N) C[(size_t)r * ldc + cc] = acc[i][j];
        }
    }
}

// causal depthwise conv (K=4) + bias + SiLU over first half of xz -> xc
__global__ void k_conv(const float* __restrict__ xz, const float* __restrict__ conv_w,
                       const float* __restrict__ conv_b, float* __restrict__ xc) {
    int i = blockIdx.x * 256 + threadIdx.x;
    if (i >= NTOK * DIN) return;
    int d   = i & (DIN - 1);
    int tok = i >> 11;
    int s   = tok & (SS - 1);
    int b   = tok >> 11;
    float v = conv_b[d];
    #pragma unroll
    for (int k = 0; k < KC; k++) {
        int ss = s - (KC - 1) + k;
        if (ss >= 0)
            v += xz[(size_t)(b * SS + ss) * (2 * DIN) + d] * conv_w[d * KC + k];
    }
    xc[i] = silu_f(v);
}

// delta = softplus(raw + dt_proj_b) in place
__global__ void k_softplus(float* __restrict__ delta, const float* __restrict__ dtb) {
    int i = blockIdx.x * 256 + threadIdx.x;
    if (i >= NTOK * DIN) return;
    int d = i & (DIN - 1);
    float v = delta[i] + dtb[d];
    delta[i] = fmaxf(v, 0.f) + log1pf(__expf(-fabsf(v)));
}

// sequential selective scan; one thread per (b,d) channel; y overwrites delta buffer
__global__ void k_scan(float* __restrict__ delta_y,            // [NTOK, DIN] in: delta, out: gated y
                       const float* __restrict__ xc,           // [NTOK, DIN]
                       const float* __restrict__ xz,           // [NTOK, 2*DIN] (z in 2nd half)
                       const float* __restrict__ x_dbl,        // [NTOK, 96]
                       const float* __restrict__ A_log,        // [DIN, 16]
                       const float* __restrict__ D_skip) {     // [DIN]
    int idx = blockIdx.x * 256 + threadIdx.x;
    if (idx >= BB * DIN) return;
    int b = idx / DIN;
    int d = idx % DIN;
    float Arow[NST], h[NST];
    #pragma unroll
    for (int n = 0; n < NST; n++) { Arow[n] = -__expf(A_log[d * NST + n]); h[n] = 0.f; }
    float Dv = D_skip[d];
    for (int s = 0; s < SS; s++) {
        size_t tok = (size_t)b * SS + s;
        float dlt = delta_y[tok * DIN + d];
        float u   = xc[tok * DIN + d];
        const float* bc = x_dbl + tok * 96;
        float du = dlt * u;
        float y = 0.f;
        #pragma unroll
        for (int n = 0; n < NST; n++) {
            float dA = __expf(dlt * Arow[n]);
            h[n] = dA * h[n] + du * bc[RDT + n];
            y += h[n] * bc[RDT + NST + n];
        }
        float z  = xz[tok * (2 * DIN) + DIN + d];
        float yf = (y + u * Dv) * silu_f(z);
        delta_y[tok * DIN + d] = yf;
    }
}

// out = x + gate * y_proj
__global__ void k_final(const float* __restrict__ x, const float* __restrict__ mod,
                        const float* __restrict__ yp, float* __restrict__ out) {
    int i = blockIdx.x * 256 + threadIdx.x;
    if (i >= NTOK * D_MODEL) return;
    int e   = i & (D_MODEL - 1);
    int tok = i >> 10;
    int b   = tok >> 11;
    out[i] = x[i] + mod[(size_t)b * 3 * D_MODEL + 2 * D_MODEL + e] * yp[i];
}

extern "C" void kernel_launch(void* const* d_in, const int* in_sizes, int n_in,
                              void* d_out, int out_size, void* d_ws, size_t ws_size,
                              hipStream_t stream) {
    const float* x         = (const float*)d_in[0];
    const float* c         = (const float*)d_in[1];
    // d_in[2] = w (unused by reference)
    const float* ln_w      = (const float*)d_in[3];
    const float* ln_b      = (const float*)d_in[4];
    const float* ada_w     = (const float*)d_in[5];
    const float* ada_b     = (const float*)d_in[6];
    const float* in_proj_w = (const float*)d_in[7];
    const float* conv_w    = (const float*)d_in[8];
    const float* conv_b    = (const float*)d_in[9];
    const float* x_proj_w  = (const float*)d_in[10];
    const float* dt_proj_w = (const float*)d_in[11];
    const float* dt_proj_b = (const float*)d_in[12];
    const float* A_log     = (const float*)d_in[13];
    const float* D_skip    = (const float*)d_in[14];
    const float* out_proj_w= (const float*)d_in[15];
    float* out = (float*)d_out;

    float* ws = (float*)d_ws;
    size_t off = 0;
    float* mod   = ws + off; off += (size_t)BB * 3 * D_MODEL;          // 6144
    float* xs    = ws + off; off += (size_t)NTOK * D_MODEL;            // 4.19M (reused as y_out)
    float* xz    = ws + off; off += (size_t)NTOK * 2 * DIN;            // 16.8M
    float* xc    = ws + off; off += (size_t)NTOK * DIN;                // 8.39M
    float* x_dbl = ws + off; off += (size_t)NTOK * 96;                 // 0.39M
    float* delta = ws + off; off += (size_t)NTOK * DIN;                // 8.39M (reused as y)
    float* y_out = xs;  // xs free after in_proj GEMM

    // 1. adaLN modulation
    k_adaln<<<dim3((BB * 3 * D_MODEL) / 4), dim3(256), 0, stream>>>(c, ada_w, ada_b, mod);
    // 2. LayerNorm + modulate
    k_lnmod<<<dim3(NTOK), dim3(256), 0, stream>>>(x, ln_w, ln_b, mod, xs);
    // 3. in_proj: xz = xs @ in_proj_w^T   [4096,1024]x[1024,4096]
    k_gemm<<<dim3((2 * DIN) / 64, NTOK / 64), dim3(256), 0, stream>>>(
        xs, D_MODEL, in_proj_w, xz, 2 * DIN, NTOK, 2 * DIN, D_MODEL);
    // 4. depthwise conv + SiLU
    k_conv<<<dim3((NTOK * DIN) / 256), dim3(256), 0, stream>>>(xz, conv_w, conv_b, xc);
    // 5. x_proj: x_dbl = xc @ x_proj_w^T   [4096,2048]x[2048,96]
    k_gemm<<<dim3((96 + 63) / 64, NTOK / 64), dim3(256), 0, stream>>>(
        xc, DIN, x_proj_w, x_dbl, 96, NTOK, 96, DIN);
    // 6. dt_proj: delta_raw = dt @ dt_proj_w^T   [4096,64]x[64,2048]
    k_gemm<<<dim3(DIN / 64, NTOK / 64), dim3(256), 0, stream>>>(
        x_dbl, 96, dt_proj_w, delta, DIN, NTOK, DIN, RDT);
    // 7. softplus(+bias)
    k_softplus<<<dim3((NTOK * DIN) / 256), dim3(256), 0, stream>>>(delta, dt_proj_b);
    // 8. selective scan + D-skip + SiLU(z) gating (y overwrites delta)
    k_scan<<<dim3((BB * DIN) / 256), dim3(256), 0, stream>>>(
        delta, xc, xz, x_dbl, A_log, D_skip);
    // 9. out_proj: y_out = y @ out_proj_w^T   [4096,2048]x[2048,1024]
    k_gemm<<<dim3(D_MODEL / 64, NTOK / 64), dim3(256), 0, stream>>>(
        delta, DIN, out_proj_w, y_out, D_MODEL, NTOK, D_MODEL, DIN);
    // 10. residual + gate
    k_final<<<dim3((NTOK * D_MODEL) / 256), dim3(256), 0, stream>>>(x, mod, y_out, out);
}

// Round 2
// 1298.946 us; speedup vs baseline: 3.2476x; 3.2476x over previous
//
#include <hip/hip_runtime.h>
#include <math.h>

#define D_MODEL 1024
#define DIN     2048      // d_inner
#define NST     16        // d_state
#define RDT     64        // dt_rank
#define KC      4         // d_conv
#define BB      2
#define SS      2048
#define NTOK    (BB*SS)   // 4096
#define NCH     32        // scan chunks
#define CL      (SS/NCH)  // 64 steps per chunk
#define QOFF    ((size_t)BB*NCH*DIN*NST)   // offset of q-array inside PQ

__device__ __forceinline__ float silu_f(float v) {
    return v / (1.f + __expf(-v));
}
__device__ __forceinline__ float softplus_f(float v) {
    return fmaxf(v, 0.f) + log1pf(__expf(-fabsf(v)));
}

// mod[b,e] = sum_j silu(c[b,j]) * ada_w[e,j] + ada_b[e];  one wave per output
__global__ void k_adaln(const float* __restrict__ c, const float* __restrict__ ada_w,
                        const float* __restrict__ ada_b, float* __restrict__ mod) {
    int wid  = (blockIdx.x * blockDim.x + threadIdx.x) >> 6;
    int lane = threadIdx.x & 63;
    if (wid >= BB * 3 * D_MODEL) return;
    int b = wid / (3 * D_MODEL);
    int e = wid % (3 * D_MODEL);
    const float* crow = c + (size_t)b * 2 * D_MODEL;
    const float* wrow = ada_w + (size_t)e * 2 * D_MODEL;
    float acc = 0.f;
    for (int j = lane; j < 2 * D_MODEL; j += 64)
        acc += silu_f(crow[j]) * wrow[j];
    for (int off = 32; off > 0; off >>= 1) acc += __shfl_down(acc, off, 64);
    if (lane == 0) mod[(size_t)b * 3 * D_MODEL + e] = acc + ada_b[e];
}

// per-token LayerNorm + adaLN modulation -> xs
__global__ void k_lnmod(const float* __restrict__ x, const float* __restrict__ ln_w,
                        const float* __restrict__ ln_b, const float* __restrict__ mod,
                        float* __restrict__ xs) {
    int tok = blockIdx.x;
    int b   = tok / SS;
    const float* xrow = x + (size_t)tok * D_MODEL;
    float s1 = 0.f, s2 = 0.f;
    for (int i = threadIdx.x; i < D_MODEL; i += 256) {
        float v = xrow[i]; s1 += v; s2 += v * v;
    }
    __shared__ float red1[4], red2[4];
    for (int off = 32; off > 0; off >>= 1) {
        s1 += __shfl_down(s1, off, 64);
        s2 += __shfl_down(s2, off, 64);
    }
    int wid = threadIdx.x >> 6, lane = threadIdx.x & 63;
    if (lane == 0) { red1[wid] = s1; red2[wid] = s2; }
    __syncthreads();
    s1 = red1[0] + red1[1] + red1[2] + red1[3];
    s2 = red2[0] + red2[1] + red2[2] + red2[3];
    float mu   = s1 / D_MODEL;
    float var  = s2 / D_MODEL - mu * mu;
    float rstd = rsqrtf(var + 1e-5f);
    const float* shiftp = mod + (size_t)b * 3 * D_MODEL;
    const float* scalep = shiftp + D_MODEL;
    float* orow = xs + (size_t)tok * D_MODEL;
    for (int i = threadIdx.x; i < D_MODEL; i += 256) {
        float v = (xrow[i] - mu) * rstd * ln_w[i] + ln_b[i];
        orow[i] = v * (1.f + scalep[i]) + shiftp[i];
    }
}

// C[M,N] = A[M,K] (row stride lda) @ W[N,K]^T ; 64x64 tile, BK=16, 256 thr, 4x4/thr
__global__ void k_gemm(const float* __restrict__ A, int lda,
                       const float* __restrict__ W,
                       float* __restrict__ C, int ldc,
                       int M, int N, int K) {
    __shared__ float As[16][68];
    __shared__ float Ws[16][68];
    int t = threadIdx.x;
    int row0 = blockIdx.y * 64;
    int col0 = blockIdx.x * 64;
    int lr = t >> 2;          // 0..63
    int lk = (t & 3) * 4;     // 0,4,8,12
    int ty = t >> 4, tx = t & 15;
    float acc[4][4] = {};
    for (int k0 = 0; k0 < K; k0 += 16) {
        const float* ap = A + (size_t)(row0 + lr) * lda + k0 + lk;
        float a0 = ap[0], a1 = ap[1], a2 = ap[2], a3 = ap[3];
        int wn = col0 + lr;
        float b0 = 0.f, b1 = 0.f, b2 = 0.f, b3 = 0.f;
        if (wn < N) {
            const float* wp = W + (size_t)wn * K + k0 + lk;
            b0 = wp[0]; b1 = wp[1]; b2 = wp[2]; b3 = wp[3];
        }
        __syncthreads();
        As[lk + 0][lr] = a0; As[lk + 1][lr] = a1; As[lk + 2][lr] = a2; As[lk + 3][lr] = a3;
        Ws[lk + 0][lr] = b0; Ws[lk + 1][lr] = b1; Ws[lk + 2][lr] = b2; Ws[lk + 3][lr] = b3;
        __syncthreads();
        #pragma unroll
        for (int kk = 0; kk < 16; kk++) {
            float av[4], bv[4];
            #pragma unroll
            for (int i = 0; i < 4; i++) av[i] = As[kk][ty * 4 + i];
            #pragma unroll
            for (int j = 0; j < 4; j++) bv[j] = Ws[kk][tx * 4 + j];
            #pragma unroll
            for (int i = 0; i < 4; i++)
                #pragma unroll
                for (int j = 0; j < 4; j++)
                    acc[i][j] += av[i] * bv[j];
        }
    }
    #pragma unroll
    for (int i = 0; i < 4; i++) {
        int r = row0 + ty * 4 + i;
        #pragma unroll
        for (int j = 0; j < 4; j++) {
            int cc = col0 + tx * 4 + j;
            if (cc < N) C[(size_t)r * ldc + cc] = acc[i][j];
        }
    }
}

// causal depthwise conv (K=4) + bias + SiLU over first half of xz -> xc
__global__ void k_conv(const float* __restrict__ xz, const float* __restrict__ conv_w,
                       const float* __restrict__ conv_b, float* __restrict__ xc) {
    int i = blockIdx.x * 256 + threadIdx.x;
    if (i >= NTOK * DIN) return;
    int d   = i & (DIN - 1);
    int tok = i >> 11;
    int s   = tok & (SS - 1);
    int b   = tok >> 11;
    float v = conv_b[d];
    #pragma unroll
    for (int k = 0; k < KC; k++) {
        int ss = s - (KC - 1) + k;
        if (ss >= 0)
            v += xz[(size_t)(b * SS + ss) * (2 * DIN) + d] * conv_w[d * KC + k];
    }
    xc[i] = silu_f(v);
}

// ---- chunked parallel scan ----
// pass 1: per (b, chunk, d) compute chunk transition P[16] and zero-state q[16]
__global__ void k_scan1(const float* __restrict__ dtraw, const float* __restrict__ dtb,
                        const float* __restrict__ xc, const float* __restrict__ x_dbl,
                        const float* __restrict__ A_log, float* __restrict__ PQ) {
    int idx = blockIdx.x * 256 + threadIdx.x;       // ((b*NCH + c)*DIN + d)
    int d = idx & (DIN - 1);
    int c = (idx >> 11) & (NCH - 1);
    int b = idx >> 16;
    float Arow[NST], P[NST], q[NST];
    #pragma unroll
    for (int n = 0; n < NST; n++) {
        Arow[n] = -__expf(A_log[d * NST + n]);
        P[n] = 1.f; q[n] = 0.f;
    }
    float bias = dtb[d];
    int tok0 = b * SS + c * CL;
    for (int s = 0; s < CL; s++) {
        size_t tok = tok0 + s;
        float v   = dtraw[tok * DIN + d] + bias;
        float dlt = softplus_f(v);
        float du  = dlt * xc[tok * DIN + d];
        const float* bc = x_dbl + tok * 96 + RDT;
        #pragma unroll
        for (int n = 0; n < NST; n++) {
            float dA = __expf(dlt * Arow[n]);
            P[n] = P[n] * dA;
            q[n] = dA * q[n] + du * bc[n];
        }
    }
    size_t o = (size_t)idx * NST;
    float4* Pp = (float4*)(PQ + o);
    float4* qp = (float4*)(PQ + QOFF + o);
    #pragma unroll
    for (int n = 0; n < 4; n++) {
        Pp[n] = make_float4(P[4*n], P[4*n+1], P[4*n+2], P[4*n+3]);
        qp[n] = make_float4(q[4*n], q[4*n+1], q[4*n+2], q[4*n+3]);
    }
}

// pass 2: per (b,d,n) combine chunks sequentially; overwrite q-slot with h0 per chunk
__global__ void k_scan2(float* __restrict__ PQ) {
    int idx = blockIdx.x * 256 + threadIdx.x;        // b*DIN*NST + d*NST + n
    int n = idx & (NST - 1);
    int d = (idx >> 4) & (DIN - 1);
    int b = idx >> 15;
    float h = 0.f;
    for (int c = 0; c < NCH; c++) {
        size_t o = ((size_t)((b * NCH + c) * DIN + d)) * NST + n;
        float P  = PQ[o];
        float qv = PQ[QOFF + o];
        PQ[QOFF + o] = h;       // h0 entering chunk c
        h = P * h + qv;
    }
}

// pass 3: per (b, chunk, d) re-run recurrence from h0, emit gated y (overwrites dtraw)
__global__ void k_scan3(float* __restrict__ dtraw_y, const float* __restrict__ dtb,
                        const float* __restrict__ xc, const float* __restrict__ xz,
                        const float* __restrict__ x_dbl, const float* __restrict__ A_log,
                        const float* __restrict__ D_skip, const float* __restrict__ PQ) {
    int idx = blockIdx.x * 256 + threadIdx.x;
    int d = idx & (DIN - 1);
    int c = (idx >> 11) & (NCH - 1);
    int b = idx >> 16;
    float Arow[NST], h[NST];
    size_t o = (size_t)idx * NST;
    const float4* h0p = (const float4*)(PQ + QOFF + o);
    #pragma unroll
    for (int n = 0; n < 4; n++) {
        float4 v = h0p[n];
        h[4*n] = v.x; h[4*n+1] = v.y; h[4*n+2] = v.z; h[4*n+3] = v.w;
    }
    #pragma unroll
    for (int n = 0; n < NST; n++) Arow[n] = -__expf(A_log[d * NST + n]);
    float bias = dtb[d];
    float Dv   = D_skip[d];
    int tok0 = b * SS + c * CL;
    for (int s = 0; s < CL; s++) {
        size_t tok = tok0 + s;
        float v   = dtraw_y[tok * DIN + d] + bias;
        float dlt = softplus_f(v);
        float u   = xc[tok * DIN + d];
        float du  = dlt * u;
        const float* bc = x_dbl + tok * 96;
        float y = 0.f;
        #pragma unroll
        for (int n = 0; n < NST; n++) {
            float dA = __expf(dlt * Arow[n]);
            h[n] = dA * h[n] + du * bc[RDT + n];
            y += h[n] * bc[RDT + NST + n];
        }
        float z  = xz[tok * (2 * DIN) + DIN + d];
        dtraw_y[tok * DIN + d] = (y + u * Dv) * silu_f(z);
    }
}

// out = x + gate * y_proj
__global__ void k_final(const float* __restrict__ x, const float* __restrict__ mod,
                        const float* __restrict__ yp, float* __restrict__ out) {
    int i = blockIdx.x * 256 + threadIdx.x;
    if (i >= NTOK * D_MODEL) return;
    int e   = i & (D_MODEL - 1);
    int tok = i >> 10;
    int b   = tok >> 11;
    out[i] = x[i] + mod[(size_t)b * 3 * D_MODEL + 2 * D_MODEL + e] * yp[i];
}

extern "C" void kernel_launch(void* const* d_in, const int* in_sizes, int n_in,
                              void* d_out, int out_size, void* d_ws, size_t ws_size,
                              hipStream_t stream) {
    const float* x         = (const float*)d_in[0];
    const float* c         = (const float*)d_in[1];
    const float* ln_w      = (const float*)d_in[3];
    const float* ln_b      = (const float*)d_in[4];
    const float* ada_w     = (const float*)d_in[5];
    const float* ada_b     = (const float*)d_in[6];
    const float* in_proj_w = (const float*)d_in[7];
    const float* conv_w    = (const float*)d_in[8];
    const float* conv_b    = (const float*)d_in[9];
    const float* x_proj_w  = (const float*)d_in[10];
    const float* dt_proj_w = (const float*)d_in[11];
    const float* dt_proj_b = (const float*)d_in[12];
    const float* A_log     = (const float*)d_in[13];
    const float* D_skip    = (const float*)d_in[14];
    const float* out_proj_w= (const float*)d_in[15];
    float* out = (float*)d_out;

    float* ws = (float*)d_ws;
    size_t off = 0;
    float* mod   = ws + off; off += (size_t)BB * 3 * D_MODEL;          // 6144
    float* xs    = ws + off; off += (size_t)NTOK * D_MODEL;            // 4.19M floats (reused: PQ, then y_out)
    float* xz    = ws + off; off += (size_t)NTOK * 2 * DIN;            // 16.8M
    float* xc    = ws + off; off += (size_t)NTOK * DIN;                // 8.39M
    float* x_dbl = ws + off; off += (size_t)NTOK * 96;                 // 0.39M
    float* delta = ws + off; off += (size_t)NTOK * DIN;                // 8.39M (raw dt, then y)
    float* PQ    = xs;   // xs free after in_proj GEMM; 2*QOFF = 4.19M floats, exact fit
    float* y_out = xs;   // free again after scan3 consumed PQ

    // 1. adaLN modulation
    k_adaln<<<dim3((BB * 3 * D_MODEL) / 4), dim3(256), 0, stream>>>(c, ada_w, ada_b, mod);
    // 2. LayerNorm + modulate
    k_lnmod<<<dim3(NTOK), dim3(256), 0, stream>>>(x, ln_w, ln_b, mod, xs);
    // 3. in_proj: xz = xs @ in_proj_w^T   [4096,1024]x[1024,4096]
    k_gemm<<<dim3((2 * DIN) / 64, NTOK / 64), dim3(256), 0, stream>>>(
        xs, D_MODEL, in_proj_w, xz, 2 * DIN, NTOK, 2 * DIN, D_MODEL);
    // 4. depthwise conv + SiLU
    k_conv<<<dim3((NTOK * DIN) / 256), dim3(256), 0, stream>>>(xz, conv_w, conv_b, xc);
    // 5. x_proj: x_dbl = xc @ x_proj_w^T   [4096,2048]x[2048,96]
    k_gemm<<<dim3((96 + 63) / 64, NTOK / 64), dim3(256), 0, stream>>>(
        xc, DIN, x_proj_w, x_dbl, 96, NTOK, 96, DIN);
    // 6. dt_proj: delta_raw = dt @ dt_proj_w^T   [4096,64]x[64,2048]  (bias fused into scan)
    k_gemm<<<dim3(DIN / 64, NTOK / 64), dim3(256), 0, stream>>>(
        x_dbl, 96, dt_proj_w, delta, DIN, NTOK, DIN, RDT);
    // 7-9. chunked parallel selective scan (softplus+bias, D-skip, SiLU(z) gate fused)
    k_scan1<<<dim3((BB * NCH * DIN) / 256), dim3(256), 0, stream>>>(
        delta, dt_proj_b, xc, x_dbl, A_log, PQ);
    k_scan2<<<dim3((BB * DIN * NST) / 256), dim3(256), 0, stream>>>(PQ);
    k_scan3<<<dim3((BB * NCH * DIN) / 256), dim3(256), 0, stream>>>(
        delta, dt_proj_b, xc, xz, x_dbl, A_log, D_skip, PQ);
    // 10. out_proj: y_out = y @ out_proj_w^T   [4096,2048]x[2048,1024]
    k_gemm<<<dim3(D_MODEL / 64, NTOK / 64), dim3(256), 0, stream>>>(
        delta, DIN, out_proj_w, y_out, D_MODEL, NTOK, D_MODEL, DIN);
    // 11. residual + gate
    k_final<<<dim3((NTOK * D_MODEL) / 256), dim3(256), 0, stream>>>(x, mod, y_out, out);
}

// Round 3
// 691.570 us; speedup vs baseline: 6.0998x; 1.8783x over previous
//
#include <hip/hip_runtime.h>
#include <hip/hip_bf16.h>
#include <math.h>

#define D_MODEL 1024
#define DIN     2048      // d_inner
#define NST     16        // d_state
#define RDT     64        // dt_rank
#define KC      4         // d_conv
#define BB      2
#define SS      2048
#define NTOK    (BB*SS)   // 4096
#define NCH     32        // scan chunks
#define CL      (SS/NCH)  // 64 steps per chunk
#define QOFF    ((size_t)BB*NCH*DIN*NST)   // offset of q-array inside PQ

typedef short short8 __attribute__((ext_vector_type(8)));
typedef float floatx4 __attribute__((ext_vector_type(4)));

__device__ __forceinline__ float silu_f(float v) {
    return v / (1.f + __expf(-v));
}
__device__ __forceinline__ float softplus_f(float v) {
    return fmaxf(v, 0.f) + log1pf(__expf(-fabsf(v)));
}
__device__ __forceinline__ unsigned short f2bf(float f) {
    __hip_bfloat16 h = __float2bfloat16(f);
    unsigned short u; __builtin_memcpy(&u, &h, 2); return u;
}
__device__ __forceinline__ float bf2f(unsigned short u) {
    __hip_bfloat16 h; __builtin_memcpy(&h, &u, 2); return __bfloat162float(h);
}
__device__ __forceinline__ void gload16(const void* g, void* l) {
    __builtin_amdgcn_global_load_lds(
        (const __attribute__((address_space(1))) void*)g,
        (__attribute__((address_space(3))) void*)l, 16, 0, 0);
}

// fp32 -> bf16 cast, 4 elems/thread
__global__ void k_cast(const float* __restrict__ src, unsigned short* __restrict__ dst) {
    int i = (blockIdx.x * 256 + threadIdx.x) * 4;
    float4 v = *(const float4*)(src + i);
    ushort4 o;
    o.x = f2bf(v.x); o.y = f2bf(v.y); o.z = f2bf(v.z); o.w = f2bf(v.w);
    *(ushort4*)(dst + i) = o;
}

// mod[b,e] = sum_j silu(c[b,j]) * ada_w[e,j] + ada_b[e];  one wave per output
__global__ void k_adaln(const float* __restrict__ c, const float* __restrict__ ada_w,
                        const float* __restrict__ ada_b, float* __restrict__ mod) {
    int wid  = (blockIdx.x * blockDim.x + threadIdx.x) >> 6;
    int lane = threadIdx.x & 63;
    if (wid >= BB * 3 * D_MODEL) return;
    int b = wid / (3 * D_MODEL);
    int e = wid % (3 * D_MODEL);
    const float* crow = c + (size_t)b * 2 * D_MODEL;
    const float* wrow = ada_w + (size_t)e * 2 * D_MODEL;
    float acc = 0.f;
    for (int j = lane; j < 2 * D_MODEL; j += 64)
        acc += silu_f(crow[j]) * wrow[j];
    for (int off = 32; off > 0; off >>= 1) acc += __shfl_down(acc, off, 64);
    if (lane == 0) mod[(size_t)b * 3 * D_MODEL + e] = acc + ada_b[e];
}

// per-token LayerNorm + adaLN modulation -> xs (bf16)
__global__ void k_lnmod(const float* __restrict__ x, const float* __restrict__ ln_w,
                        const float* __restrict__ ln_b, const float* __restrict__ mod,
                        unsigned short* __restrict__ xs) {
    int tok = blockIdx.x;
    int b   = tok / SS;
    const float* xrow = x + (size_t)tok * D_MODEL;
    float s1 = 0.f, s2 = 0.f;
    for (int i = threadIdx.x; i < D_MODEL; i += 256) {
        float v = xrow[i]; s1 += v; s2 += v * v;
    }
    __shared__ float red1[4], red2[4];
    for (int off = 32; off > 0; off >>= 1) {
        s1 += __shfl_down(s1, off, 64);
        s2 += __shfl_down(s2, off, 64);
    }
    int wid = threadIdx.x >> 6, lane = threadIdx.x & 63;
    if (lane == 0) { red1[wid] = s1; red2[wid] = s2; }
    __syncthreads();
    s1 = red1[0] + red1[1] + red1[2] + red1[3];
    s2 = red2[0] + red2[1] + red2[2] + red2[3];
    float mu   = s1 / D_MODEL;
    float var  = s2 / D_MODEL - mu * mu;
    float rstd = rsqrtf(var + 1e-5f);
    const float* shiftp = mod + (size_t)b * 3 * D_MODEL;
    const float* scalep = shiftp + D_MODEL;
    unsigned short* orow = xs + (size_t)tok * D_MODEL;
    for (int i = threadIdx.x; i < D_MODEL; i += 256) {
        float v = (xrow[i] - mu) * rstd * ln_w[i] + ln_b[i];
        orow[i] = f2bf(v * (1.f + scalep[i]) + shiftp[i]);
    }
}

// bf16 MFMA GEMM: C[M,N] = A[M,K](bf16, row-major) @ W[N,K](bf16)^T
// 128x128 tile, BK=32, 256 thr (4 waves), 4x4 mfma_f32_16x16x32_bf16 per wave.
// LDS chunk-major [kchunk(4)][row(128)][8 bf16] staged via global_load_lds w=16.
template <typename OutT>
__global__ void k_mfma_gemm(const unsigned short* __restrict__ A,
                            const unsigned short* __restrict__ W,
                            OutT* __restrict__ C, int ldc, int K) {
    __shared__ short lA[4 * 128 * 8];   // 8 KB
    __shared__ short lB[4 * 128 * 8];   // 8 KB
    int t    = threadIdx.x;
    int lane = t & 63;
    int w    = t >> 6;
    int wm   = (w & 1) * 64, wn = (w >> 1) * 64;
    int quad = lane >> 4, l15 = lane & 15;
    int row0 = blockIdx.y * 128;
    int col0 = blockIdx.x * 128;

    int s1 = t, s2 = t + 256;           // lds 16B slot ids (lane-contiguous per wave)
    const unsigned short* ga1 = A + (size_t)(row0 + (s1 & 127)) * K + (s1 >> 7) * 8;
    const unsigned short* ga2 = A + (size_t)(row0 + (s2 & 127)) * K + (s2 >> 7) * 8;
    const unsigned short* gb1 = W + (size_t)(col0 + (s1 & 127)) * K + (s1 >> 7) * 8;
    const unsigned short* gb2 = W + (size_t)(col0 + (s2 & 127)) * K + (s2 >> 7) * 8;

    const short8* A8 = (const short8*)lA;
    const short8* B8 = (const short8*)lB;
    floatx4 acc[4][4] = {};

    for (int k0 = 0; k0 < K; k0 += 32) {
        gload16(ga1 + k0, lA + s1 * 8);
        gload16(ga2 + k0, lA + s2 * 8);
        gload16(gb1 + k0, lB + s1 * 8);
        gload16(gb2 + k0, lB + s2 * 8);
        __builtin_amdgcn_s_waitcnt(0);
        __syncthreads();
        short8 af[4], bfr[4];
        #pragma unroll
        for (int i = 0; i < 4; i++) af[i]  = A8[quad * 128 + wm + i * 16 + l15];
        #pragma unroll
        for (int j = 0; j < 4; j++) bfr[j] = B8[quad * 128 + wn + j * 16 + l15];
        #pragma unroll
        for (int i = 0; i < 4; i++)
            #pragma unroll
            for (int j = 0; j < 4; j++)
                acc[i][j] = __builtin_amdgcn_mfma_f32_16x16x32_bf16(
                    af[i], bfr[j], acc[i][j], 0, 0, 0);
        __syncthreads();
    }
    // C/D layout: col = lane&15, row = quad*4 + reg  [verified m89/m91]
    #pragma unroll
    for (int i = 0; i < 4; i++) {
        int r0 = row0 + wm + i * 16 + quad * 4;
        #pragma unroll
        for (int j = 0; j < 4; j++) {
            int cc = col0 + wn + j * 16 + l15;
            #pragma unroll
            for (int rg = 0; rg < 4; rg++) {
                float v = acc[i][j][rg];
                if constexpr (sizeof(OutT) == 2) {
                    C[(size_t)(r0 + rg) * ldc + cc] = (OutT)f2bf(v);
                } else {
                    C[(size_t)(r0 + rg) * ldc + cc] = (OutT)v;
                }
            }
        }
    }
}

// fp32 GEMM (small matmuls): C[M,N] = A[M,K] @ W[N,K]^T ; 64x64 tile
__global__ void k_gemm(const float* __restrict__ A, int lda,
                       const float* __restrict__ W,
                       float* __restrict__ C, int ldc,
                       int M, int N, int K) {
    __shared__ float As[16][68];
    __shared__ float Ws[16][68];
    int t = threadIdx.x;
    int row0 = blockIdx.y * 64;
    int col0 = blockIdx.x * 64;
    int lr = t >> 2;
    int lk = (t & 3) * 4;
    int ty = t >> 4, tx = t & 15;
    float acc[4][4] = {};
    for (int k0 = 0; k0 < K; k0 += 16) {
        const float* ap = A + (size_t)(row0 + lr) * lda + k0 + lk;
        float a0 = ap[0], a1 = ap[1], a2 = ap[2], a3 = ap[3];
        int wn = col0 + lr;
        float b0 = 0.f, b1 = 0.f, b2 = 0.f, b3 = 0.f;
        if (wn < N) {
            const float* wp = W + (size_t)wn * K + k0 + lk;
            b0 = wp[0]; b1 = wp[1]; b2 = wp[2]; b3 = wp[3];
        }
        __syncthreads();
        As[lk + 0][lr] = a0; As[lk + 1][lr] = a1; As[lk + 2][lr] = a2; As[lk + 3][lr] = a3;
        Ws[lk + 0][lr] = b0; Ws[lk + 1][lr] = b1; Ws[lk + 2][lr] = b2; Ws[lk + 3][lr] = b3;
        __syncthreads();
        #pragma unroll
        for (int kk = 0; kk < 16; kk++) {
            float av[4], bv[4];
            #pragma unroll
            for (int i = 0; i < 4; i++) av[i] = As[kk][ty * 4 + i];
            #pragma unroll
            for (int j = 0; j < 4; j++) bv[j] = Ws[kk][tx * 4 + j];
            #pragma unroll
            for (int i = 0; i < 4; i++)
                #pragma unroll
                for (int j = 0; j < 4; j++)
                    acc[i][j] += av[i] * bv[j];
        }
    }
    #pragma unroll
    for (int i = 0; i < 4; i++) {
        int r = row0 + ty * 4 + i;
        #pragma unroll
        for (int j = 0; j < 4; j++) {
            int cc = col0 + tx * 4 + j;
            if (cc < N) C[(size_t)r * ldc + cc] = acc[i][j];
        }
    }
}

// causal depthwise conv (K=4) + bias + SiLU over first half of xz(bf16) -> xc(fp32)
__global__ void k_conv(const unsigned short* __restrict__ xz, const float* __restrict__ conv_w,
                       const float* __restrict__ conv_b, float* __restrict__ xc) {
    int i = blockIdx.x * 256 + threadIdx.x;
    if (i >= NTOK * DIN) return;
    int d   = i & (DIN - 1);
    int tok = i >> 11;
    int s   = tok & (SS - 1);
    int b   = tok >> 11;
    float v = conv_b[d];
    #pragma unroll
    for (int k = 0; k < KC; k++) {
        int ss = s - (KC - 1) + k;
        if (ss >= 0)
            v += bf2f(xz[(size_t)(b * SS + ss) * (2 * DIN) + d]) * conv_w[d * KC + k];
    }
    xc[i] = silu_f(v);
}

// ---- chunked parallel scan ----
__global__ void k_scan1(const float* __restrict__ dtraw, const float* __restrict__ dtb,
                        const float* __restrict__ xc, const float* __restrict__ x_dbl,
                        const float* __restrict__ A_log, float* __restrict__ PQ) {
    int idx = blockIdx.x * 256 + threadIdx.x;       // ((b*NCH + c)*DIN + d)
    int d = idx & (DIN - 1);
    int c = (idx >> 11) & (NCH - 1);
    int b = idx >> 16;
    float Arow[NST], P[NST], q[NST];
    #pragma unroll
    for (int n = 0; n < NST; n++) {
        Arow[n] = -__expf(A_log[d * NST + n]);
        P[n] = 1.f; q[n] = 0.f;
    }
    float bias = dtb[d];
    int tok0 = b * SS + c * CL;
    for (int s = 0; s < CL; s++) {
        size_t tok = tok0 + s;
        float v   = dtraw[tok * DIN + d] + bias;
        float dlt = softplus_f(v);
        float du  = dlt * xc[tok * DIN + d];
        const float* bc = x_dbl + tok * 96 + RDT;
        #pragma unroll
        for (int n = 0; n < NST; n++) {
            float dA = __expf(dlt * Arow[n]);
            P[n] = P[n] * dA;
            q[n] = dA * q[n] + du * bc[n];
        }
    }
    size_t o = (size_t)idx * NST;
    float4* Pp = (float4*)(PQ + o);
    float4* qp = (float4*)(PQ + QOFF + o);
    #pragma unroll
    for (int n = 0; n < 4; n++) {
        Pp[n] = make_float4(P[4*n], P[4*n+1], P[4*n+2], P[4*n+3]);
        qp[n] = make_float4(q[4*n], q[4*n+1], q[4*n+2], q[4*n+3]);
    }
}

__global__ void k_scan2(float* __restrict__ PQ) {
    int idx = blockIdx.x * 256 + threadIdx.x;        // b*DIN*NST + d*NST + n
    int n = idx & (NST - 1);
    int d = (idx >> 4) & (DIN - 1);
    int b = idx >> 15;
    float h = 0.f;
    for (int c = 0; c < NCH; c++) {
        size_t o = ((size_t)((b * NCH + c) * DIN + d)) * NST + n;
        float P  = PQ[o];
        float qv = PQ[QOFF + o];
        PQ[QOFF + o] = h;       // h0 entering chunk c
        h = P * h + qv;
    }
}

// pass 3: re-run recurrence from h0, emit gated y as bf16
__global__ void k_scan3(const float* __restrict__ dtraw, const float* __restrict__ dtb,
                        const float* __restrict__ xc, const unsigned short* __restrict__ xz,
                        const float* __restrict__ x_dbl, const float* __restrict__ A_log,
                        const float* __restrict__ D_skip, const float* __restrict__ PQ,
                        unsigned short* __restrict__ y_bf) {
    int idx = blockIdx.x * 256 + threadIdx.x;
    int d = idx & (DIN - 1);
    int c = (idx >> 11) & (NCH - 1);
    int b = idx >> 16;
    float Arow[NST], h[NST];
    size_t o = (size_t)idx * NST;
    const float4* h0p = (const float4*)(PQ + QOFF + o);
    #pragma unroll
    for (int n = 0; n < 4; n++) {
        float4 v = h0p[n];
        h[4*n] = v.x; h[4*n+1] = v.y; h[4*n+2] = v.z; h[4*n+3] = v.w;
    }
    #pragma unroll
    for (int n = 0; n < NST; n++) Arow[n] = -__expf(A_log[d * NST + n]);
    float bias = dtb[d];
    float Dv   = D_skip[d];
    int tok0 = b * SS + c * CL;
    for (int s = 0; s < CL; s++) {
        size_t tok = tok0 + s;
        float v   = dtraw[tok * DIN + d] + bias;
        float dlt = softplus_f(v);
        float u   = xc[tok * DIN + d];
        float du  = dlt * u;
        const float* bc = x_dbl + tok * 96;
        float y = 0.f;
        #pragma unroll
        for (int n = 0; n < NST; n++) {
            float dA = __expf(dlt * Arow[n]);
            h[n] = dA * h[n] + du * bc[RDT + n];
            y += h[n] * bc[RDT + NST + n];
        }
        float z  = bf2f(xz[tok * (2 * DIN) + DIN + d]);
        y_bf[tok * DIN + d] = f2bf((y + u * Dv) * silu_f(z));
    }
}

// out = x + gate * y_proj
__global__ void k_final(const float* __restrict__ x, const float* __restrict__ mod,
                        const float* __restrict__ yp, float* __restrict__ out) {
    int i = blockIdx.x * 256 + threadIdx.x;
    if (i >= NTOK * D_MODEL) return;
    int e   = i & (D_MODEL - 1);
    int tok = i >> 10;
    int b   = tok >> 11;
    out[i] = x[i] + mod[(size_t)b * 3 * D_MODEL + 2 * D_MODEL + e] * yp[i];
}

extern "C" void kernel_launch(void* const* d_in, const int* in_sizes, int n_in,
                              void* d_out, int out_size, void* d_ws, size_t ws_size,
                              hipStream_t stream) {
    const float* x         = (const float*)d_in[0];
    const float* c         = (const float*)d_in[1];
    const float* ln_w      = (const float*)d_in[3];
    const float* ln_b      = (const float*)d_in[4];
    const float* ada_w     = (const float*)d_in[5];
    const float* ada_b     = (const float*)d_in[6];
    const float* in_proj_w = (const float*)d_in[7];
    const float* conv_w    = (const float*)d_in[8];
    const float* conv_b    = (const float*)d_in[9];
    const float* x_proj_w  = (const float*)d_in[10];
    const float* dt_proj_w = (const float*)d_in[11];
    const float* dt_proj_b = (const float*)d_in[12];
    const float* A_log     = (const float*)d_in[13];
    const float* D_skip    = (const float*)d_in[14];
    const float* out_proj_w= (const float*)d_in[15];
    float* out = (float*)d_out;

    float* ws = (float*)d_ws;
    size_t off = 0;
    float* mod            = ws + off; off += (size_t)BB * 3 * D_MODEL;
    unsigned short* xs_bf = (unsigned short*)(ws + off); off += (size_t)NTOK * D_MODEL / 2;
    unsigned short* xz_bf = (unsigned short*)(ws + off); off += (size_t)NTOK * 2 * DIN / 2;
    float* xc             = ws + off; off += (size_t)NTOK * DIN;
    float* x_dbl          = ws + off; off += (size_t)NTOK * 96;
    float* delta          = ws + off; off += (size_t)NTOK * DIN;
    float* PQ             = ws + off; off += 2 * QOFF;
    unsigned short* y_bf  = (unsigned short*)(ws + off); off += (size_t)NTOK * DIN / 2;
    // aliases (lifetimes disjoint):
    unsigned short* w_in_bf  = (unsigned short*)PQ;     // dead before scan1 writes PQ
    unsigned short* w_out_bf = xz_bf;                   // xz dead after scan3
    float* y_out             = delta;                   // delta dead after scan3

    // 0. cast in_proj_w to bf16
    k_cast<<<dim3((2 * DIN * D_MODEL) / 1024), dim3(256), 0, stream>>>(in_proj_w, w_in_bf);
    // 1. adaLN modulation
    k_adaln<<<dim3((BB * 3 * D_MODEL) / 4), dim3(256), 0, stream>>>(c, ada_w, ada_b, mod);
    // 2. LayerNorm + modulate -> bf16
    k_lnmod<<<dim3(NTOK), dim3(256), 0, stream>>>(x, ln_w, ln_b, mod, xs_bf);
    // 3. in_proj (bf16 MFMA): xz = xs @ in_proj_w^T  [4096,1024]x[1024,4096]
    k_mfma_gemm<unsigned short><<<dim3((2 * DIN) / 128, NTOK / 128), dim3(256), 0, stream>>>(
        xs_bf, w_in_bf, xz_bf, 2 * DIN, D_MODEL);
    // 4. depthwise conv + SiLU
    k_conv<<<dim3((NTOK * DIN) / 256), dim3(256), 0, stream>>>(xz_bf, conv_w, conv_b, xc);
    // 5. x_proj (fp32): x_dbl = xc @ x_proj_w^T  [4096,2048]x[2048,96]
    k_gemm<<<dim3((96 + 63) / 64, NTOK / 64), dim3(256), 0, stream>>>(
        xc, DIN, x_proj_w, x_dbl, 96, NTOK, 96, DIN);
    // 6. dt_proj (fp32): delta_raw = dt @ dt_proj_w^T  [4096,64]x[64,2048]
    k_gemm<<<dim3(DIN / 64, NTOK / 64), dim3(256), 0, stream>>>(
        x_dbl, 96, dt_proj_w, delta, DIN, NTOK, DIN, RDT);
    // 7-9. chunked parallel selective scan
    k_scan1<<<dim3((BB * NCH * DIN) / 256), dim3(256), 0, stream>>>(
        delta, dt_proj_b, xc, x_dbl, A_log, PQ);
    k_scan2<<<dim3((BB * DIN * NST) / 256), dim3(256), 0, stream>>>(PQ);
    k_scan3<<<dim3((BB * NCH * DIN) / 256), dim3(256), 0, stream>>>(
        delta, dt_proj_b, xc, xz_bf, x_dbl, A_log, D_skip, PQ, y_bf);
    // 10. cast out_proj_w to bf16 (xz region now dead)
    k_cast<<<dim3((D_MODEL * DIN) / 1024), dim3(256), 0, stream>>>(out_proj_w, w_out_bf);
    // 11. out_proj (bf16 MFMA): y_out = y @ out_proj_w^T  [4096,2048]x[2048,1024]
    k_mfma_gemm<float><<<dim3(D_MODEL / 128, NTOK / 128), dim3(256), 0, stream>>>(
        y_bf, w_out_bf, y_out, D_MODEL, DIN);
    // 12. residual + gate
    k_final<<<dim3((NTOK * D_MODEL) / 256), dim3(256), 0, stream>>>(x, mod, y_out, out);
}

// Round 4
// 537.549 us; speedup vs baseline: 7.8475x; 1.2865x over previous
//
#include <hip/hip_runtime.h>
#include <hip/hip_bf16.h>
#include <math.h>

#define D_MODEL 1024
#define DIN     2048      // d_inner
#define NST     16        // d_state
#define RDT     64        // dt_rank
#define KC      4         // d_conv
#define BB      2
#define SS      2048
#define NTOK    (BB*SS)   // 4096
#define NCH     64        // scan chunks
#define CL      (SS/NCH)  // 32 steps per chunk
#define QOFF    ((size_t)BB*NCH*DIN*NST)   // offset of q-array inside PQ
#define LOG2E   1.4426950408889634f

typedef short short8 __attribute__((ext_vector_type(8)));
typedef float floatx4 __attribute__((ext_vector_type(4)));

__device__ __forceinline__ float silu_f(float v) {
    return v / (1.f + __expf(-v));
}
__device__ __forceinline__ float softplus_f(float v) {
    return fmaxf(v, 0.f) + log1pf(__expf(-fabsf(v)));
}
__device__ __forceinline__ unsigned short f2bf(float f) {
    __hip_bfloat16 h = __float2bfloat16(f);
    unsigned short u; __builtin_memcpy(&u, &h, 2); return u;
}
__device__ __forceinline__ float bf2f(unsigned short u) {
    __hip_bfloat16 h; __builtin_memcpy(&h, &u, 2); return __bfloat162float(h);
}
__device__ __forceinline__ void gload16(const void* g, void* l) {
    __builtin_amdgcn_global_load_lds(
        (const __attribute__((address_space(1))) void*)g,
        (__attribute__((address_space(3))) void*)l, 16, 0, 0);
}

// fp32 -> bf16 cast, 4 elems/thread
__global__ void k_cast(const float* __restrict__ src, unsigned short* __restrict__ dst) {
    int i = (blockIdx.x * 256 + threadIdx.x) * 4;
    float4 v = *(const float4*)(src + i);
    ushort4 o;
    o.x = f2bf(v.x); o.y = f2bf(v.y); o.z = f2bf(v.z); o.w = f2bf(v.w);
    *(ushort4*)(dst + i) = o;
}

// mod[b,e] = sum_j silu(c[b,j]) * ada_w[e,j] + ada_b[e];  one wave per output
__global__ void k_adaln(const float* __restrict__ c, const float* __restrict__ ada_w,
                        const float* __restrict__ ada_b, float* __restrict__ mod) {
    int wid  = (blockIdx.x * blockDim.x + threadIdx.x) >> 6;
    int lane = threadIdx.x & 63;
    if (wid >= BB * 3 * D_MODEL) return;
    int b = wid / (3 * D_MODEL);
    int e = wid % (3 * D_MODEL);
    const float* crow = c + (size_t)b * 2 * D_MODEL;
    const float* wrow = ada_w + (size_t)e * 2 * D_MODEL;
    float acc = 0.f;
    for (int j = lane; j < 2 * D_MODEL; j += 64)
        acc += silu_f(crow[j]) * wrow[j];
    for (int off = 32; off > 0; off >>= 1) acc += __shfl_down(acc, off, 64);
    if (lane == 0) mod[(size_t)b * 3 * D_MODEL + e] = acc + ada_b[e];
}

// per-token LayerNorm + adaLN modulation -> xs (bf16)
__global__ void k_lnmod(const float* __restrict__ x, const float* __restrict__ ln_w,
                        const float* __restrict__ ln_b, const float* __restrict__ mod,
                        unsigned short* __restrict__ xs) {
    int tok = blockIdx.x;
    int b   = tok / SS;
    const float* xrow = x + (size_t)tok * D_MODEL;
    float s1 = 0.f, s2 = 0.f;
    for (int i = threadIdx.x; i < D_MODEL; i += 256) {
        float v = xrow[i]; s1 += v; s2 += v * v;
    }
    __shared__ float red1[4], red2[4];
    for (int off = 32; off > 0; off >>= 1) {
        s1 += __shfl_down(s1, off, 64);
        s2 += __shfl_down(s2, off, 64);
    }
    int wid = threadIdx.x >> 6, lane = threadIdx.x & 63;
    if (lane == 0) { red1[wid] = s1; red2[wid] = s2; }
    __syncthreads();
    s1 = red1[0] + red1[1] + red1[2] + red1[3];
    s2 = red2[0] + red2[1] + red2[2] + red2[3];
    float mu   = s1 / D_MODEL;
    float var  = s2 / D_MODEL - mu * mu;
    float rstd = rsqrtf(var + 1e-5f);
    const float* shiftp = mod + (size_t)b * 3 * D_MODEL;
    const float* scalep = shiftp + D_MODEL;
    unsigned short* orow = xs + (size_t)tok * D_MODEL;
    for (int i = threadIdx.x; i < D_MODEL; i += 256) {
        float v = (xrow[i] - mu) * rstd * ln_w[i] + ln_b[i];
        orow[i] = f2bf(v * (1.f + scalep[i]) + shiftp[i]);
    }
}

// bf16 MFMA GEMM: C[M,N] = A[M,K](bf16) @ W[N,K](bf16)^T ; 128x128 tile, BK=32
template <typename OutT>
__global__ void k_mfma_gemm(const unsigned short* __restrict__ A,
                            const unsigned short* __restrict__ W,
                            OutT* __restrict__ C, int ldc, int K) {
    __shared__ short lA[4 * 128 * 8];
    __shared__ short lB[4 * 128 * 8];
    int t    = threadIdx.x;
    int lane = t & 63;
    int w    = t >> 6;
    int wm   = (w & 1) * 64, wn = (w >> 1) * 64;
    int quad = lane >> 4, l15 = lane & 15;
    int row0 = blockIdx.y * 128;
    int col0 = blockIdx.x * 128;

    int s1 = t, s2 = t + 256;
    const unsigned short* ga1 = A + (size_t)(row0 + (s1 & 127)) * K + (s1 >> 7) * 8;
    const unsigned short* ga2 = A + (size_t)(row0 + (s2 & 127)) * K + (s2 >> 7) * 8;
    const unsigned short* gb1 = W + (size_t)(col0 + (s1 & 127)) * K + (s1 >> 7) * 8;
    const unsigned short* gb2 = W + (size_t)(col0 + (s2 & 127)) * K + (s2 >> 7) * 8;

    const short8* A8 = (const short8*)lA;
    const short8* B8 = (const short8*)lB;
    floatx4 acc[4][4] = {};

    for (int k0 = 0; k0 < K; k0 += 32) {
        gload16(ga1 + k0, lA + s1 * 8);
        gload16(ga2 + k0, lA + s2 * 8);
        gload16(gb1 + k0, lB + s1 * 8);
        gload16(gb2 + k0, lB + s2 * 8);
        __builtin_amdgcn_s_waitcnt(0);
        __syncthreads();
        short8 af[4], bfr[4];
        #pragma unroll
        for (int i = 0; i < 4; i++) af[i]  = A8[quad * 128 + wm + i * 16 + l15];
        #pragma unroll
        for (int j = 0; j < 4; j++) bfr[j] = B8[quad * 128 + wn + j * 16 + l15];
        #pragma unroll
        for (int i = 0; i < 4; i++)
            #pragma unroll
            for (int j = 0; j < 4; j++)
                acc[i][j] = __builtin_amdgcn_mfma_f32_16x16x32_bf16(
                    af[i], bfr[j], acc[i][j], 0, 0, 0);
        __syncthreads();
    }
    #pragma unroll
    for (int i = 0; i < 4; i++) {
        int r0 = row0 + wm + i * 16 + quad * 4;
        #pragma unroll
        for (int j = 0; j < 4; j++) {
            int cc = col0 + wn + j * 16 + l15;
            #pragma unroll
            for (int rg = 0; rg < 4; rg++) {
                float v = acc[i][j][rg];
                if constexpr (sizeof(OutT) == 2) {
                    C[(size_t)(r0 + rg) * ldc + cc] = (OutT)f2bf(v);
                } else {
                    C[(size_t)(r0 + rg) * ldc + cc] = (OutT)v;
                }
            }
        }
    }
}

// fp32 GEMM: C[M,N] = A[M,K] @ W[N,K]^T ; 64x64 tile; optional softplus(v+bias) epilogue
__global__ void k_gemm(const float* __restrict__ A, int lda,
                       const float* __restrict__ W,
                       float* __restrict__ C, int ldc,
                       int M, int N, int K,
                       const float* __restrict__ bias_sp) {
    __shared__ float As[16][68];
    __shared__ float Ws[16][68];
    int t = threadIdx.x;
    int row0 = blockIdx.y * 64;
    int col0 = blockIdx.x * 64;
    int lr = t >> 2;
    int lk = (t & 3) * 4;
    int ty = t >> 4, tx = t & 15;
    float acc[4][4] = {};
    for (int k0 = 0; k0 < K; k0 += 16) {
        const float* ap = A + (size_t)(row0 + lr) * lda + k0 + lk;
        float a0 = ap[0], a1 = ap[1], a2 = ap[2], a3 = ap[3];
        int wn = col0 + lr;
        float b0 = 0.f, b1 = 0.f, b2 = 0.f, b3 = 0.f;
        if (wn < N) {
            const float* wp = W + (size_t)wn * K + k0 + lk;
            b0 = wp[0]; b1 = wp[1]; b2 = wp[2]; b3 = wp[3];
        }
        __syncthreads();
        As[lk + 0][lr] = a0; As[lk + 1][lr] = a1; As[lk + 2][lr] = a2; As[lk + 3][lr] = a3;
        Ws[lk + 0][lr] = b0; Ws[lk + 1][lr] = b1; Ws[lk + 2][lr] = b2; Ws[lk + 3][lr] = b3;
        __syncthreads();
        #pragma unroll
        for (int kk = 0; kk < 16; kk++) {
            float av[4], bv[4];
            #pragma unroll
            for (int i = 0; i < 4; i++) av[i] = As[kk][ty * 4 + i];
            #pragma unroll
            for (int j = 0; j < 4; j++) bv[j] = Ws[kk][tx * 4 + j];
            #pragma unroll
            for (int i = 0; i < 4; i++)
                #pragma unroll
                for (int j = 0; j < 4; j++)
                    acc[i][j] += av[i] * bv[j];
        }
    }
    #pragma unroll
    for (int i = 0; i < 4; i++) {
        int r = row0 + ty * 4 + i;
        #pragma unroll
        for (int j = 0; j < 4; j++) {
            int cc = col0 + tx * 4 + j;
            if (cc < N) {
                float v = acc[i][j];
                if (bias_sp) v = softplus_f(v + bias_sp[cc]);
                C[(size_t)r * ldc + cc] = v;
            }
        }
    }
}

// split-K fp32 GEMM for x_proj: partial[z] = A[:, z*KS:(z+1)*KS] @ W[:, z*KS:..]^T
#define XP_KS 512
__global__ void k_gemm_sk(const float* __restrict__ A, int lda,
                          const float* __restrict__ W, int Kfull,
                          float* __restrict__ part, int ldc, int M, int N) {
    __shared__ float As[16][68];
    __shared__ float Ws[16][68];
    int t = threadIdx.x;
    int row0 = blockIdx.y * 64;
    int col0 = blockIdx.x * 64;
    int kbase = blockIdx.z * XP_KS;
    int lr = t >> 2;
    int lk = (t & 3) * 4;
    int ty = t >> 4, tx = t & 15;
    float acc[4][4] = {};
    for (int k0 = kbase; k0 < kbase + XP_KS; k0 += 16) {
        const float* ap = A + (size_t)(row0 + lr) * lda + k0 + lk;
        float a0 = ap[0], a1 = ap[1], a2 = ap[2], a3 = ap[3];
        int wn = col0 + lr;
        float b0 = 0.f, b1 = 0.f, b2 = 0.f, b3 = 0.f;
        if (wn < N) {
            const float* wp = W + (size_t)wn * Kfull + k0 + lk;
            b0 = wp[0]; b1 = wp[1]; b2 = wp[2]; b3 = wp[3];
        }
        __syncthreads();
        As[lk + 0][lr] = a0; As[lk + 1][lr] = a1; As[lk + 2][lr] = a2; As[lk + 3][lr] = a3;
        Ws[lk + 0][lr] = b0; Ws[lk + 1][lr] = b1; Ws[lk + 2][lr] = b2; Ws[lk + 3][lr] = b3;
        __syncthreads();
        #pragma unroll
        for (int kk = 0; kk < 16; kk++) {
            float av[4], bv[4];
            #pragma unroll
            for (int i = 0; i < 4; i++) av[i] = As[kk][ty * 4 + i];
            #pragma unroll
            for (int j = 0; j < 4; j++) bv[j] = Ws[kk][tx * 4 + j];
            #pragma unroll
            for (int i = 0; i < 4; i++)
                #pragma unroll
                for (int j = 0; j < 4; j++)
                    acc[i][j] += av[i] * bv[j];
        }
    }
    float* Cz = part + (size_t)blockIdx.z * M * ldc;
    #pragma unroll
    for (int i = 0; i < 4; i++) {
        int r = row0 + ty * 4 + i;
        #pragma unroll
        for (int j = 0; j < 4; j++) {
            int cc = col0 + tx * 4 + j;
            if (cc < N) Cz[(size_t)r * ldc + cc] = acc[i][j];
        }
    }
}

// reduce 4 split-K partials -> x_dbl
__global__ void k_red4(const float* __restrict__ part, float* __restrict__ x_dbl) {
    int i = (blockIdx.x * 256 + threadIdx.x) * 4;
    const size_t SZ = (size_t)NTOK * 96;
    float4 a = *(const float4*)(part + i);
    float4 b = *(const float4*)(part + SZ + i);
    float4 c = *(const float4*)(part + 2 * SZ + i);
    float4 d = *(const float4*)(part + 3 * SZ + i);
    float4 o;
    o.x = a.x + b.x + c.x + d.x;
    o.y = a.y + b.y + c.y + d.y;
    o.z = a.z + b.z + c.z + d.z;
    o.w = a.w + b.w + c.w + d.w;
    *(float4*)(x_dbl + i) = o;
}

// causal depthwise conv (K=4) + bias + SiLU over first half of xz(bf16) -> xc(fp32)
__global__ void k_conv(const unsigned short* __restrict__ xz, const float* __restrict__ conv_w,
                       const float* __restrict__ conv_b, float* __restrict__ xc) {
    int i = blockIdx.x * 256 + threadIdx.x;
    if (i >= NTOK * DIN) return;
    int d   = i & (DIN - 1);
    int tok = i >> 11;
    int s   = tok & (SS - 1);
    int b   = tok >> 11;
    float v = conv_b[d];
    #pragma unroll
    for (int k = 0; k < KC; k++) {
        int ss = s - (KC - 1) + k;
        if (ss >= 0)
            v += bf2f(xz[(size_t)(b * SS + ss) * (2 * DIN) + d]) * conv_w[d * KC + k];
    }
    xc[i] = silu_f(v);
}

// ---- chunked parallel scan (delta already softplus'ed by dt_proj epilogue) ----
// pass 1: per (b,chunk,d): chunk-sum of delta -> P = exp2(A2*sdlt); q via recurrence.
__global__ void k_scan1(const float* __restrict__ delta,
                        const float* __restrict__ xc, const float* __restrict__ x_dbl,
                        const float* __restrict__ A_log, float* __restrict__ PQ) {
    __shared__ float bS[CL][NST];        // B rows for this chunk (uniform per block)
    int idx = blockIdx.x * 256 + threadIdx.x;       // ((b*NCH + c)*DIN + d)
    int d = idx & (DIN - 1);
    int c = (idx >> 11) & (NCH - 1);
    int b = idx >> 17;
    int tok0 = b * SS + c * CL;
    for (int f = threadIdx.x; f < CL * NST; f += 256) {
        int s = f >> 4, n = f & 15;
        bS[s][n] = x_dbl[(size_t)(tok0 + s) * 96 + RDT + n];
    }
    float A2[NST], q[NST];
    #pragma unroll
    for (int n = 0; n < NST; n++) {
        A2[n] = -__expf(A_log[d * NST + n]) * LOG2E;
        q[n] = 0.f;
    }
    __syncthreads();
    size_t base = (size_t)tok0 * DIN + d;
    float sdlt = 0.f;
    float pd[4], pu[4];
    #pragma unroll
    for (int j = 0; j < 4; j++) { pd[j] = delta[base + j * DIN]; pu[j] = xc[base + j * DIN]; }
    for (int g = 0; g < CL / 4; g++) {
        float cd[4], cu[4];
        #pragma unroll
        for (int j = 0; j < 4; j++) { cd[j] = pd[j]; cu[j] = pu[j]; }
        if (g + 1 < CL / 4) {
            size_t nb = base + (size_t)(g * 4 + 4) * DIN;
            #pragma unroll
            for (int j = 0; j < 4; j++) { pd[j] = delta[nb + j * DIN]; pu[j] = xc[nb + j * DIN]; }
        }
        #pragma unroll
        for (int js = 0; js < 4; js++) {
            int s = g * 4 + js;
            float dlt = cd[js];
            float du  = dlt * cu[js];
            sdlt += dlt;
            #pragma unroll
            for (int n = 0; n < NST; n++) {
                float dA = exp2f(dlt * A2[n]);
                q[n] = dA * q[n] + du * bS[s][n];
            }
        }
    }
    size_t o = (size_t)idx * NST;
    float4* Pp = (float4*)(PQ + o);
    float4* qp = (float4*)(PQ + QOFF + o);
    #pragma unroll
    for (int n = 0; n < 4; n++) {
        Pp[n] = make_float4(exp2f(A2[4*n] * sdlt), exp2f(A2[4*n+1] * sdlt),
                            exp2f(A2[4*n+2] * sdlt), exp2f(A2[4*n+3] * sdlt));
        qp[n] = make_float4(q[4*n], q[4*n+1], q[4*n+2], q[4*n+3]);
    }
}

// pass 2: per (b,d,n) combine chunks sequentially; overwrite q-slot with h0 per chunk
__global__ void k_scan2(float* __restrict__ PQ) {
    int idx = blockIdx.x * 256 + threadIdx.x;        // b*DIN*NST + d*NST + n
    int n = idx & (NST - 1);
    int d = (idx >> 4) & (DIN - 1);
    int b = idx >> 15;
    float h = 0.f;
    #pragma unroll 4
    for (int c = 0; c < NCH; c++) {
        size_t o = ((size_t)((b * NCH + c) * DIN + d)) * NST + n;
        float P  = PQ[o];
        float qv = PQ[QOFF + o];
        PQ[QOFF + o] = h;       // h0 entering chunk c
        h = P * h + qv;
    }
}

// pass 3: re-run recurrence from h0, emit gated y as bf16
__global__ void k_scan3(const float* __restrict__ delta,
                        const float* __restrict__ xc, const unsigned short* __restrict__ xz,
                        const float* __restrict__ x_dbl, const float* __restrict__ A_log,
                        const float* __restrict__ D_skip, const float* __restrict__ PQ,
                        unsigned short* __restrict__ y_bf) {
    __shared__ float bcS[CL][2 * NST];   // B and C rows (uniform per block)
    int idx = blockIdx.x * 256 + threadIdx.x;
    int d = idx & (DIN - 1);
    int c = (idx >> 11) & (NCH - 1);
    int b = idx >> 17;
    int tok0 = b * SS + c * CL;
    for (int f = threadIdx.x; f < CL * 2 * NST; f += 256) {
        int s = f >> 5, j = f & 31;
        bcS[s][j] = x_dbl[(size_t)(tok0 + s) * 96 + RDT + j];
    }
    float A2[NST], h[NST];
    size_t o = (size_t)idx * NST;
    const float4* h0p = (const float4*)(PQ + QOFF + o);
    #pragma unroll
    for (int n = 0; n < 4; n++) {
        float4 v = h0p[n];
        h[4*n] = v.x; h[4*n+1] = v.y; h[4*n+2] = v.z; h[4*n+3] = v.w;
    }
    #pragma unroll
    for (int n = 0; n < NST; n++) A2[n] = -__expf(A_log[d * NST + n]) * LOG2E;
    float Dv = D_skip[d];
    __syncthreads();
    size_t base  = (size_t)tok0 * DIN + d;
    size_t zbase = (size_t)tok0 * 2 * DIN + DIN + d;
    float pd[4], pu[4]; unsigned short pz[4];
    #pragma unroll
    for (int j = 0; j < 4; j++) {
        pd[j] = delta[base + j * DIN];
        pu[j] = xc[base + j * DIN];
        pz[j] = xz[zbase + (size_t)j * 2 * DIN];
    }
    for (int g = 0; g < CL / 4; g++) {
        float cd[4], cu[4]; unsigned short cz[4];
        #pragma unroll
        for (int j = 0; j < 4; j++) { cd[j] = pd[j]; cu[j] = pu[j]; cz[j] = pz[j]; }
        if (g + 1 < CL / 4) {
            size_t nb = base + (size_t)(g * 4 + 4) * DIN;
            size_t nz = zbase + (size_t)(g * 4 + 4) * 2 * DIN;
            #pragma unroll
            for (int j = 0; j < 4; j++) {
                pd[j] = delta[nb + j * DIN];
                pu[j] = xc[nb + j * DIN];
                pz[j] = xz[nz + (size_t)j * 2 * DIN];
            }
        }
        #pragma unroll
        for (int js = 0; js < 4; js++) {
            int s = g * 4 + js;
            float dlt = cd[js];
            float u   = cu[js];
            float du  = dlt * u;
            float y = 0.f;
            #pragma unroll
            for (int n = 0; n < NST; n++) {
                float dA = exp2f(dlt * A2[n]);
                h[n] = dA * h[n] + du * bcS[s][n];
                y += h[n] * bcS[s][NST + n];
            }
            float z = bf2f(cz[js]);
            y_bf[base + (size_t)s * DIN] = f2bf((y + u * Dv) * silu_f(z));
        }
    }
}

// out = x + gate * y_proj
__global__ void k_final(const float* __restrict__ x, const float* __restrict__ mod,
                        const float* __restrict__ yp, float* __restrict__ out) {
    int i = blockIdx.x * 256 + threadIdx.x;
    if (i >= NTOK * D_MODEL) return;
    int e   = i & (D_MODEL - 1);
    int tok = i >> 10;
    int b   = tok >> 11;
    out[i] = x[i] + mod[(size_t)b * 3 * D_MODEL + 2 * D_MODEL + e] * yp[i];
}

extern "C" void kernel_launch(void* const* d_in, const int* in_sizes, int n_in,
                              void* d_out, int out_size, void* d_ws, size_t ws_size,
                              hipStream_t stream) {
    const float* x         = (const float*)d_in[0];
    const float* c         = (const float*)d_in[1];
    const float* ln_w      = (const float*)d_in[3];
    const float* ln_b      = (const float*)d_in[4];
    const float* ada_w     = (const float*)d_in[5];
    const float* ada_b     = (const float*)d_in[6];
    const float* in_proj_w = (const float*)d_in[7];
    const float* conv_w    = (const float*)d_in[8];
    const float* conv_b    = (const float*)d_in[9];
    const float* x_proj_w  = (const float*)d_in[10];
    const float* dt_proj_w = (const float*)d_in[11];
    const float* dt_proj_b = (const float*)d_in[12];
    const float* A_log     = (const float*)d_in[13];
    const float* D_skip    = (const float*)d_in[14];
    const float* out_proj_w= (const float*)d_in[15];
    float* out = (float*)d_out;

    float* ws = (float*)d_ws;
    size_t off = 0;
    float* mod            = ws + off; off += (size_t)BB * 3 * D_MODEL;
    unsigned short* xs_bf = (unsigned short*)(ws + off); off += (size_t)NTOK * D_MODEL / 2;
    unsigned short* xz_bf = (unsigned short*)(ws + off); off += (size_t)NTOK * 2 * DIN / 2;
    float* xc             = ws + off; off += (size_t)NTOK * DIN;
    float* x_dbl          = ws + off; off += (size_t)NTOK * 96;
    float* delta          = ws + off; off += (size_t)NTOK * DIN;
    float* PQ             = ws + off; off += 2 * QOFF;
    unsigned short* y_bf  = (unsigned short*)(ws + off); off += (size_t)NTOK * DIN / 2;
    float* xp_part        = ws + off; off += (size_t)4 * NTOK * 96;
    // aliases (lifetimes disjoint):
    unsigned short* w_in_bf  = (unsigned short*)PQ;     // dead before scan1 writes PQ
    unsigned short* w_out_bf = xz_bf;                   // xz dead after scan3
    float* y_out             = delta;                   // delta dead after scan3

    // 0. cast in_proj_w to bf16
    k_cast<<<dim3((2 * DIN * D_MODEL) / 1024), dim3(256), 0, stream>>>(in_proj_w, w_in_bf);
    // 1. adaLN modulation
    k_adaln<<<dim3((BB * 3 * D_MODEL) / 4), dim3(256), 0, stream>>>(c, ada_w, ada_b, mod);
    // 2. LayerNorm + modulate -> bf16
    k_lnmod<<<dim3(NTOK), dim3(256), 0, stream>>>(x, ln_w, ln_b, mod, xs_bf);
    // 3. in_proj (bf16 MFMA): xz = xs @ in_proj_w^T  [4096,1024]x[1024,4096]
    k_mfma_gemm<unsigned short><<<dim3((2 * DIN) / 128, NTOK / 128), dim3(256), 0, stream>>>(
        xs_bf, w_in_bf, xz_bf, 2 * DIN, D_MODEL);
    // 4. depthwise conv + SiLU
    k_conv<<<dim3((NTOK * DIN) / 256), dim3(256), 0, stream>>>(xz_bf, conv_w, conv_b, xc);
    // 5. x_proj (fp32 split-K x4): x_dbl = xc @ x_proj_w^T  [4096,2048]x[2048,96]
    k_gemm_sk<<<dim3(2, NTOK / 64, 4), dim3(256), 0, stream>>>(
        xc, DIN, x_proj_w, DIN, xp_part, 96, NTOK, 96);
    k_red4<<<dim3((NTOK * 96) / 1024), dim3(256), 0, stream>>>(xp_part, x_dbl);
    // 6. dt_proj (fp32) + fused softplus(v + dt_proj_b): delta = softplus(dt @ dt_proj_w^T + b)
    k_gemm<<<dim3(DIN / 64, NTOK / 64), dim3(256), 0, stream>>>(
        x_dbl, 96, dt_proj_w, delta, DIN, NTOK, DIN, RDT, dt_proj_b);
    // 7-9. chunked parallel selective scan
    k_scan1<<<dim3((BB * NCH * DIN) / 256), dim3(256), 0, stream>>>(
        delta, xc, x_dbl, A_log, PQ);
    k_scan2<<<dim3((BB * DIN * NST) / 256), dim3(256), 0, stream>>>(PQ);
    k_scan3<<<dim3((BB * NCH * DIN) / 256), dim3(256), 0, stream>>>(
        delta, xc, xz_bf, x_dbl, A_log, D_skip, PQ, y_bf);
    // 10. cast out_proj_w to bf16 (xz region now dead)
    k_cast<<<dim3((D_MODEL * DIN) / 1024), dim3(256), 0, stream>>>(out_proj_w, w_out_bf);
    // 11. out_proj (bf16 MFMA): y_out = y @ out_proj_w^T  [4096,2048]x[2048,1024]
    k_mfma_gemm<float><<<dim3(D_MODEL / 128, NTOK / 128), dim3(256), 0, stream>>>(
        y_bf, w_out_bf, y_out, D_MODEL, DIN);
    // 12. residual + gate
    k_final<<<dim3((NTOK * D_MODEL) / 256), dim3(256), 0, stream>>>(x, mod, y_out, out);
}

// Round 5
// 519.812 us; speedup vs baseline: 8.1153x; 1.0341x over previous
//
#include <hip/hip_runtime.h>
#include <hip/hip_bf16.h>
#include <math.h>

#define D_MODEL 1024
#define DIN     2048      // d_inner
#define NST     16        // d_state
#define RDT     64        // dt_rank
#define KC      4         // d_conv
#define BB      2
#define SS      2048
#define NTOK    (BB*SS)   // 4096
#define NCH     64        // scan chunks
#define CL      (SS/NCH)  // 32 steps per chunk
#define QOFF    ((size_t)BB*NCH*DIN*NST)
#define LOG2E   1.4426950408889634f

typedef short short8 __attribute__((ext_vector_type(8)));
typedef float floatx4 __attribute__((ext_vector_type(4)));

__device__ __forceinline__ float silu_f(float v) { return v / (1.f + __expf(-v)); }
__device__ __forceinline__ float softplus_f(float v) {
    return fmaxf(v, 0.f) + log1pf(__expf(-fabsf(v)));
}
__device__ __forceinline__ unsigned short f2bf(float f) {
    __hip_bfloat16 h = __float2bfloat16(f);
    unsigned short u; __builtin_memcpy(&u, &h, 2); return u;
}
__device__ __forceinline__ float bf2f(unsigned short u) {
    __hip_bfloat16 h; __builtin_memcpy(&h, &u, 2); return __bfloat162float(h);
}
__device__ __forceinline__ void gload16(const void* g, void* l) {
    __builtin_amdgcn_global_load_lds(
        (const __attribute__((address_space(1))) void*)g,
        (__attribute__((address_space(3))) void*)l, 16, 0, 0);
}

// fp32 -> bf16 cast, 4 elems/thread
__global__ void k_cast(const float* __restrict__ src, unsigned short* __restrict__ dst) {
    int i = (blockIdx.x * 256 + threadIdx.x) * 4;
    float4 v = *(const float4*)(src + i);
    ushort4 o;
    o.x = f2bf(v.x); o.y = f2bf(v.y); o.z = f2bf(v.z); o.w = f2bf(v.w);
    *(ushort4*)(dst + i) = o;
}

__global__ void k_adaln(const float* __restrict__ c, const float* __restrict__ ada_w,
                        const float* __restrict__ ada_b, float* __restrict__ mod) {
    int wid  = (blockIdx.x * blockDim.x + threadIdx.x) >> 6;
    int lane = threadIdx.x & 63;
    if (wid >= BB * 3 * D_MODEL) return;
    int b = wid / (3 * D_MODEL);
    int e = wid % (3 * D_MODEL);
    const float* crow = c + (size_t)b * 2 * D_MODEL;
    const float* wrow = ada_w + (size_t)e * 2 * D_MODEL;
    float acc = 0.f;
    for (int j = lane; j < 2 * D_MODEL; j += 64)
        acc += silu_f(crow[j]) * wrow[j];
    for (int off = 32; off > 0; off >>= 1) acc += __shfl_down(acc, off, 64);
    if (lane == 0) mod[(size_t)b * 3 * D_MODEL + e] = acc + ada_b[e];
}

__global__ void k_lnmod(const float* __restrict__ x, const float* __restrict__ ln_w,
                        const float* __restrict__ ln_b, const float* __restrict__ mod,
                        unsigned short* __restrict__ xs) {
    int tok = blockIdx.x;
    int b   = tok / SS;
    const float* xrow = x + (size_t)tok * D_MODEL;
    float s1 = 0.f, s2 = 0.f;
    for (int i = threadIdx.x; i < D_MODEL; i += 256) {
        float v = xrow[i]; s1 += v; s2 += v * v;
    }
    __shared__ float red1[4], red2[4];
    for (int off = 32; off > 0; off >>= 1) {
        s1 += __shfl_down(s1, off, 64);
        s2 += __shfl_down(s2, off, 64);
    }
    int wid = threadIdx.x >> 6, lane = threadIdx.x & 63;
    if (lane == 0) { red1[wid] = s1; red2[wid] = s2; }
    __syncthreads();
    s1 = red1[0] + red1[1] + red1[2] + red1[3];
    s2 = red2[0] + red2[1] + red2[2] + red2[3];
    float mu   = s1 / D_MODEL;
    float var  = s2 / D_MODEL - mu * mu;
    float rstd = rsqrtf(var + 1e-5f);
    const float* shiftp = mod + (size_t)b * 3 * D_MODEL;
    const float* scalep = shiftp + D_MODEL;
    unsigned short* orow = xs + (size_t)tok * D_MODEL;
    for (int i = threadIdx.x; i < D_MODEL; i += 256) {
        float v = (xrow[i] - mu) * rstd * ln_w[i] + ln_b[i];
        orow[i] = f2bf(v * (1.f + scalep[i]) + shiftp[i]);
    }
}

// ---- bf16 MFMA GEMM v2: TM=128, BK=64, templated TN and epilogue MODE ----
// MODE 0: bf16 C store via LDS-staged coalesced 16B stores (TN=128)
// MODE 1: split-K f32 partial store, N masked to 96 (x_proj; grid.z = K-slab)
// MODE 2: fused final epilogue: out = x + gate*acc, f32, TN=64
template <int TN, int MODE>
__global__ void k_mfma2(const unsigned short* __restrict__ A,
                        const unsigned short* __restrict__ W,
                        void* __restrict__ Cv, int ldc, int K,
                        const float* __restrict__ xres,
                        const float* __restrict__ mod) {
    constexpr int TM = 128;
    constexpr int MF = (TN == 128) ? 4 : 2;
    constexpr int APT = TM * 8 / 256;            // 4
    constexpr int BPT = TN * 8 / 256;            // 4 or 2
    constexpr int STAGE = (TM + TN) * 64 * 2;
    constexpr int EPI = (MODE == 0) ? TM * 136 * 2 : (MODE == 2 ? TM * 68 * 4 : 0);
    constexpr int SBYTES = STAGE > EPI ? STAGE : EPI;
    __shared__ char smem[SBYTES];
    short* lA = (short*)smem;
    short* lB = (short*)(smem + TM * 64 * 2);

    int t    = threadIdx.x;
    int lane = t & 63;
    int w    = t >> 6;
    int quad = lane >> 4, l15 = lane & 15;
    int wm   = (TN == 128) ? (w & 1) * 64 : w * 32;
    int wn   = (TN == 128) ? (w >> 1) * 64 : 0;
    int row0 = blockIdx.y * TM;
    int col0 = blockIdx.x * TN;
    int kbase = (MODE == 1) ? blockIdx.z * 256 : 0;
    int kiters = (MODE == 1) ? 256 : K;

    const unsigned short* pa[APT]; int la_[APT];
    #pragma unroll
    for (int p = 0; p < APT; p++) {
        int s = t + p * 256;
        int row = s & (TM - 1);
        int kc8 = s / TM;
        pa[p] = A + (size_t)(row0 + row) * K + kbase + kc8 * 8;
        la_[p] = s * 8;
    }
    const unsigned short* pb[BPT]; int lb_[BPT];
    #pragma unroll
    for (int p = 0; p < BPT; p++) {
        int s = t + p * 256;
        int row = s & (TN - 1);
        int kc8 = s / TN;
        int grow = col0 + row;
        if (MODE == 1) grow = grow < 95 ? grow : 95;   // clamp OOB W rows (N=96)
        pb[p] = W + (size_t)grow * K + kbase + kc8 * 8;
        lb_[p] = s * 8;
    }

    const short8* A8 = (const short8*)lA;
    const short8* B8 = (const short8*)lB;
    floatx4 acc[MF][4] = {};

    for (int k0 = 0; k0 < kiters; k0 += 64) {
        #pragma unroll
        for (int p = 0; p < APT; p++) gload16(pa[p] + k0, lA + la_[p]);
        #pragma unroll
        for (int p = 0; p < BPT; p++) gload16(pb[p] + k0, lB + lb_[p]);
        __builtin_amdgcn_s_waitcnt(0);
        __syncthreads();
        #pragma unroll
        for (int kc = 0; kc < 2; kc++) {
            short8 af[MF], bfr[4];
            #pragma unroll
            for (int i = 0; i < MF; i++) af[i]  = A8[(kc * 4 + quad) * TM + wm + i * 16 + l15];
            #pragma unroll
            for (int j = 0; j < 4; j++)  bfr[j] = B8[(kc * 4 + quad) * TN + wn + j * 16 + l15];
            #pragma unroll
            for (int i = 0; i < MF; i++)
                #pragma unroll
                for (int j = 0; j < 4; j++)
                    acc[i][j] = __builtin_amdgcn_mfma_f32_16x16x32_bf16(
                        af[i], bfr[j], acc[i][j], 0, 0, 0);
        }
        __syncthreads();
    }

    if constexpr (MODE == 0) {
        short* st = (short*)smem;
        #pragma unroll
        for (int i = 0; i < MF; i++)
            #pragma unroll
            for (int j = 0; j < 4; j++)
                #pragma unroll
                for (int rg = 0; rg < 4; rg++)
                    st[(wm + i * 16 + quad * 4 + rg) * 136 + wn + j * 16 + l15] =
                        (short)f2bf(acc[i][j][rg]);
        __syncthreads();
        unsigned short* Cc = (unsigned short*)Cv;
        #pragma unroll
        for (int p = 0; p < 8; p++) {
            int idx = p * 256 + t;
            int r = idx >> 4, sx = idx & 15;
            *(short8*)(Cc + (size_t)(row0 + r) * ldc + col0 + sx * 8) =
                *(const short8*)(st + r * 136 + sx * 8);
        }
    } else if constexpr (MODE == 1) {
        float* Cz = (float*)Cv + (size_t)blockIdx.z * NTOK * 96;
        #pragma unroll
        for (int i = 0; i < MF; i++)
            #pragma unroll
            for (int j = 0; j < 4; j++) {
                int cc = col0 + wn + j * 16 + l15;
                if (cc < 96) {
                    #pragma unroll
                    for (int rg = 0; rg < 4; rg++)
                        Cz[(size_t)(row0 + wm + i * 16 + quad * 4 + rg) * 96 + cc] =
                            acc[i][j][rg];
                }
            }
    } else {
        float* stf = (float*)smem;
        #pragma unroll
        for (int i = 0; i < MF; i++)
            #pragma unroll
            for (int j = 0; j < 4; j++)
                #pragma unroll
                for (int rg = 0; rg < 4; rg++)
                    stf[(wm + i * 16 + quad * 4 + rg) * 68 + j * 16 + l15] = acc[i][j][rg];
        __syncthreads();
        float* Co = (float*)Cv;
        #pragma unroll
        for (int p = 0; p < 8; p++) {
            int idx = p * 256 + t;
            int r = idx >> 4, sx = idx & 15;
            float4 v = *(const float4*)(stf + r * 68 + sx * 4);
            int tok = row0 + r;
            int e   = col0 + sx * 4;
            int bb  = tok >> 11;
            float4 xv = *(const float4*)(xres + (size_t)tok * D_MODEL + e);
            float4 g  = *(const float4*)(mod + (size_t)bb * 3 * D_MODEL + 2 * D_MODEL + e);
            float4 o;
            o.x = xv.x + g.x * v.x; o.y = xv.y + g.y * v.y;
            o.z = xv.z + g.z * v.z; o.w = xv.w + g.w * v.w;
            *(float4*)(Co + (size_t)tok * ldc + e) = o;
        }
    }
}

// reduce 8 split-K partials -> x_dbl (fp32)
__global__ void k_red8(const float* __restrict__ part, float* __restrict__ x_dbl) {
    int i = (blockIdx.x * 256 + threadIdx.x) * 4;
    const size_t SZ = (size_t)NTOK * 96;
    float4 s = *(const float4*)(part + i);
    #pragma unroll
    for (int z = 1; z < 8; z++) {
        float4 a = *(const float4*)(part + z * SZ + i);
        s.x += a.x; s.y += a.y; s.z += a.z; s.w += a.w;
    }
    *(float4*)(x_dbl + i) = s;
}

// fp32 GEMM (dt_proj): C = A @ W^T, softplus(v+bias) epilogue
__global__ void k_gemm(const float* __restrict__ A, int lda,
                       const float* __restrict__ W,
                       float* __restrict__ C, int ldc,
                       int M, int N, int K,
                       const float* __restrict__ bias_sp) {
    __shared__ float As[16][68];
    __shared__ float Ws[16][68];
    int t = threadIdx.x;
    int row0 = blockIdx.y * 64;
    int col0 = blockIdx.x * 64;
    int lr = t >> 2;
    int lk = (t & 3) * 4;
    int ty = t >> 4, tx = t & 15;
    float acc[4][4] = {};
    for (int k0 = 0; k0 < K; k0 += 16) {
        const float* ap = A + (size_t)(row0 + lr) * lda + k0 + lk;
        float a0 = ap[0], a1 = ap[1], a2 = ap[2], a3 = ap[3];
        int wn = col0 + lr;
        float b0 = 0.f, b1 = 0.f, b2 = 0.f, b3 = 0.f;
        if (wn < N) {
            const float* wp = W + (size_t)wn * K + k0 + lk;
            b0 = wp[0]; b1 = wp[1]; b2 = wp[2]; b3 = wp[3];
        }
        __syncthreads();
        As[lk + 0][lr] = a0; As[lk + 1][lr] = a1; As[lk + 2][lr] = a2; As[lk + 3][lr] = a3;
        Ws[lk + 0][lr] = b0; Ws[lk + 1][lr] = b1; Ws[lk + 2][lr] = b2; Ws[lk + 3][lr] = b3;
        __syncthreads();
        #pragma unroll
        for (int kk = 0; kk < 16; kk++) {
            float av[4], bv[4];
            #pragma unroll
            for (int i = 0; i < 4; i++) av[i] = As[kk][ty * 4 + i];
            #pragma unroll
            for (int j = 0; j < 4; j++) bv[j] = Ws[kk][tx * 4 + j];
            #pragma unroll
            for (int i = 0; i < 4; i++)
                #pragma unroll
                for (int j = 0; j < 4; j++)
                    acc[i][j] += av[i] * bv[j];
        }
    }
    #pragma unroll
    for (int i = 0; i < 4; i++) {
        int r = row0 + ty * 4 + i;
        #pragma unroll
        for (int j = 0; j < 4; j++) {
            int cc = col0 + tx * 4 + j;
            if (cc < N) {
                float v = acc[i][j];
                if (bias_sp) v = softplus_f(v + bias_sp[cc]);
                C[(size_t)r * ldc + cc] = v;
            }
        }
    }
}

// causal depthwise conv (K=4) + bias + SiLU -> xc (bf16)
__global__ void k_conv(const unsigned short* __restrict__ xz, const float* __restrict__ conv_w,
                       const float* __restrict__ conv_b, unsigned short* __restrict__ xc) {
    int i = blockIdx.x * 256 + threadIdx.x;
    if (i >= NTOK * DIN) return;
    int d   = i & (DIN - 1);
    int tok = i >> 11;
    int s   = tok & (SS - 1);
    int b   = tok >> 11;
    float v = conv_b[d];
    #pragma unroll
    for (int k = 0; k < KC; k++) {
        int ss = s - (KC - 1) + k;
        if (ss >= 0)
            v += bf2f(xz[(size_t)(b * SS + ss) * (2 * DIN) + d]) * conv_w[d * KC + k];
    }
    xc[i] = f2bf(silu_f(v));
}

// ---- chunked parallel scan ----
__global__ void k_scan1(const float* __restrict__ delta,
                        const unsigned short* __restrict__ xc, const float* __restrict__ x_dbl,
                        const float* __restrict__ A_log, float* __restrict__ PQ) {
    __shared__ float bS[CL][NST];
    int idx = blockIdx.x * 256 + threadIdx.x;       // ((b*NCH + c)*DIN + d)
    int d = idx & (DIN - 1);
    int c = (idx >> 11) & (NCH - 1);
    int b = idx >> 17;
    int tok0 = b * SS + c * CL;
    for (int f = threadIdx.x; f < CL * NST; f += 256) {
        int s = f >> 4, n = f & 15;
        bS[s][n] = x_dbl[(size_t)(tok0 + s) * 96 + RDT + n];
    }
    float A2[NST], q[NST];
    #pragma unroll
    for (int n = 0; n < NST; n++) {
        A2[n] = -__expf(A_log[d * NST + n]) * LOG2E;
        q[n] = 0.f;
    }
    __syncthreads();
    size_t base = (size_t)tok0 * DIN + d;
    float sdlt = 0.f;
    float pd[4], pu[4];
    #pragma unroll
    for (int j = 0; j < 4; j++) { pd[j] = delta[base + j * DIN]; pu[j] = bf2f(xc[base + j * DIN]); }
    for (int g = 0; g < CL / 4; g++) {
        float cd[4], cu[4];
        #pragma unroll
        for (int j = 0; j < 4; j++) { cd[j] = pd[j]; cu[j] = pu[j]; }
        if (g + 1 < CL / 4) {
            size_t nb = base + (size_t)(g * 4 + 4) * DIN;
            #pragma unroll
            for (int j = 0; j < 4; j++) { pd[j] = delta[nb + j * DIN]; pu[j] = bf2f(xc[nb + j * DIN]); }
        }
        #pragma unroll
        for (int js = 0; js < 4; js++) {
            int s = g * 4 + js;
            float dlt = cd[js];
            float du  = dlt * cu[js];
            sdlt += dlt;
            #pragma unroll
            for (int n = 0; n < NST; n++) {
                float dA = exp2f(dlt * A2[n]);
                q[n] = dA * q[n] + du * bS[s][n];
            }
        }
    }
    size_t o = (size_t)idx * NST;
    float4* Pp = (float4*)(PQ + o);
    float4* qp = (float4*)(PQ + QOFF + o);
    #pragma unroll
    for (int n = 0; n < 4; n++) {
        Pp[n] = make_float4(exp2f(A2[4*n] * sdlt), exp2f(A2[4*n+1] * sdlt),
                            exp2f(A2[4*n+2] * sdlt), exp2f(A2[4*n+3] * sdlt));
        qp[n] = make_float4(q[4*n], q[4*n+1], q[4*n+2], q[4*n+3]);
    }
}

__global__ void k_scan2(float* __restrict__ PQ) {
    int idx = blockIdx.x * 256 + threadIdx.x;        // b*DIN*NST + d*NST + n
    int n = idx & (NST - 1);
    int d = (idx >> 4) & (DIN - 1);
    int b = idx >> 15;
    float h = 0.f;
    #pragma unroll 4
    for (int c = 0; c < NCH; c++) {
        size_t o = ((size_t)((b * NCH + c) * DIN + d)) * NST + n;
        float P  = PQ[o];
        float qv = PQ[QOFF + o];
        PQ[QOFF + o] = h;
        h = P * h + qv;
    }
}

__global__ void k_scan3(const float* __restrict__ delta,
                        const unsigned short* __restrict__ xc, const unsigned short* __restrict__ xz,
                        const float* __restrict__ x_dbl, const float* __restrict__ A_log,
                        const float* __restrict__ D_skip, const float* __restrict__ PQ,
                        unsigned short* __restrict__ y_bf) {
    __shared__ float bcS[CL][2 * NST];
    int idx = blockIdx.x * 256 + threadIdx.x;
    int d = idx & (DIN - 1);
    int c = (idx >> 11) & (NCH - 1);
    int b = idx >> 17;
    int tok0 = b * SS + c * CL;
    for (int f = threadIdx.x; f < CL * 2 * NST; f += 256) {
        int s = f >> 5, j = f & 31;
        bcS[s][j] = x_dbl[(size_t)(tok0 + s) * 96 + RDT + j];
    }
    float A2[NST], h[NST];
    size_t o = (size_t)idx * NST;
    const float4* h0p = (const float4*)(PQ + QOFF + o);
    #pragma unroll
    for (int n = 0; n < 4; n++) {
        float4 v = h0p[n];
        h[4*n] = v.x; h[4*n+1] = v.y; h[4*n+2] = v.z; h[4*n+3] = v.w;
    }
    #pragma unroll
    for (int n = 0; n < NST; n++) A2[n] = -__expf(A_log[d * NST + n]) * LOG2E;
    float Dv = D_skip[d];
    __syncthreads();
    size_t base  = (size_t)tok0 * DIN + d;
    size_t zbase = (size_t)tok0 * 2 * DIN + DIN + d;
    float pd[4]; unsigned short pu[4], pz[4];
    #pragma unroll
    for (int j = 0; j < 4; j++) {
        pd[j] = delta[base + j * DIN];
        pu[j] = xc[base + j * DIN];
        pz[j] = xz[zbase + (size_t)j * 2 * DIN];
    }
    for (int g = 0; g < CL / 4; g++) {
        float cd[4]; unsigned short cu[4], cz[4];
        #pragma unroll
        for (int j = 0; j < 4; j++) { cd[j] = pd[j]; cu[j] = pu[j]; cz[j] = pz[j]; }
        if (g + 1 < CL / 4) {
            size_t nb = base + (size_t)(g * 4 + 4) * DIN;
            size_t nz = zbase + (size_t)(g * 4 + 4) * 2 * DIN;
            #pragma unroll
            for (int j = 0; j < 4; j++) {
                pd[j] = delta[nb + j * DIN];
                pu[j] = xc[nb + j * DIN];
                pz[j] = xz[nz + (size_t)j * 2 * DIN];
            }
        }
        #pragma unroll
        for (int js = 0; js < 4; js++) {
            int s = g * 4 + js;
            float dlt = cd[js];
            float u   = bf2f(cu[js]);
            float du  = dlt * u;
            float y = 0.f;
            #pragma unroll
            for (int n = 0; n < NST; n++) {
                float dA = exp2f(dlt * A2[n]);
                h[n] = dA * h[n] + du * bcS[s][n];
                y += h[n] * bcS[s][NST + n];
            }
            float z = bf2f(cz[js]);
            y_bf[base + (size_t)s * DIN] = f2bf((y + u * Dv) * silu_f(z));
        }
    }
}

extern "C" void kernel_launch(void* const* d_in, const int* in_sizes, int n_in,
                              void* d_out, int out_size, void* d_ws, size_t ws_size,
                              hipStream_t stream) {
    const float* x         = (const float*)d_in[0];
    const float* c         = (const float*)d_in[1];
    const float* ln_w      = (const float*)d_in[3];
    const float* ln_b      = (const float*)d_in[4];
    const float* ada_w     = (const float*)d_in[5];
    const float* ada_b     = (const float*)d_in[6];
    const float* in_proj_w = (const float*)d_in[7];
    const float* conv_w    = (const float*)d_in[8];
    const float* conv_b    = (const float*)d_in[9];
    const float* x_proj_w  = (const float*)d_in[10];
    const float* dt_proj_w = (const float*)d_in[11];
    const float* dt_proj_b = (const float*)d_in[12];
    const float* A_log     = (const float*)d_in[13];
    const float* D_skip    = (const float*)d_in[14];
    const float* out_proj_w= (const float*)d_in[15];
    float* out = (float*)d_out;

    float* ws = (float*)d_ws;
    size_t off = 0;
    float* mod            = ws + off; off += (size_t)BB * 3 * D_MODEL;
    unsigned short* xs_bf = (unsigned short*)(ws + off); off += (size_t)NTOK * D_MODEL / 2;
    unsigned short* xz_bf = (unsigned short*)(ws + off); off += (size_t)NTOK * 2 * DIN / 2;
    unsigned short* xc_bf = (unsigned short*)(ws + off); off += (size_t)NTOK * DIN / 2;
    float* x_dbl          = ws + off; off += (size_t)NTOK * 96;
    float* delta          = ws + off; off += (size_t)NTOK * DIN;
    float* PQ             = ws + off; off += 2 * QOFF;
    unsigned short* y_bf  = (unsigned short*)(ws + off); off += (size_t)NTOK * DIN / 2;
    float* xp_part        = ws + off; off += (size_t)8 * NTOK * 96;
    unsigned short* w_xp_bf = (unsigned short*)(ws + off); off += (size_t)96 * DIN / 2;
    // aliases (lifetimes disjoint):
    unsigned short* w_in_bf  = (unsigned short*)PQ;     // dead before scan1 writes PQ
    unsigned short* w_out_bf = xs_bf;                   // xs dead after in_proj

    // 0. weight casts
    k_cast<<<dim3((2 * DIN * D_MODEL) / 1024), dim3(256), 0, stream>>>(in_proj_w, w_in_bf);
    k_cast<<<dim3((96 * DIN) / 1024), dim3(256), 0, stream>>>(x_proj_w, w_xp_bf);
    // 1. adaLN modulation
    k_adaln<<<dim3((BB * 3 * D_MODEL) / 4), dim3(256), 0, stream>>>(c, ada_w, ada_b, mod);
    // 2. LayerNorm + modulate -> bf16
    k_lnmod<<<dim3(NTOK), dim3(256), 0, stream>>>(x, ln_w, ln_b, mod, xs_bf);
    // 3. in_proj (bf16 MFMA, BK=64): xz = xs @ in_proj_w^T  [4096,1024]x[1024,4096]
    k_mfma2<128, 0><<<dim3((2 * DIN) / 128, NTOK / 128), dim3(256), 0, stream>>>(
        xs_bf, w_in_bf, xz_bf, 2 * DIN, D_MODEL, nullptr, nullptr);
    // 4. cast out_proj_w (xs region now dead)
    k_cast<<<dim3((D_MODEL * DIN) / 1024), dim3(256), 0, stream>>>(out_proj_w, w_out_bf);
    // 5. depthwise conv + SiLU -> bf16
    k_conv<<<dim3((NTOK * DIN) / 256), dim3(256), 0, stream>>>(xz_bf, conv_w, conv_b, xc_bf);
    // 6. x_proj (bf16 MFMA split-K x8): xp_part[z] = xc @ x_proj_w^T slabs
    k_mfma2<128, 1><<<dim3(1, NTOK / 128, 8), dim3(256), 0, stream>>>(
        xc_bf, w_xp_bf, xp_part, 96, DIN, nullptr, nullptr);
    k_red8<<<dim3((NTOK * 96) / 1024), dim3(256), 0, stream>>>(xp_part, x_dbl);
    // 7. dt_proj (fp32) + fused softplus(v + dt_proj_b)
    k_gemm<<<dim3(DIN / 64, NTOK / 64), dim3(256), 0, stream>>>(
        x_dbl, 96, dt_proj_w, delta, DIN, NTOK, DIN, RDT, dt_proj_b);
    // 8-10. chunked parallel selective scan
    k_scan1<<<dim3((BB * NCH * DIN) / 256), dim3(256), 0, stream>>>(
        delta, xc_bf, x_dbl, A_log, PQ);
    k_scan2<<<dim3((BB * DIN * NST) / 256), dim3(256), 0, stream>>>(PQ);
    k_scan3<<<dim3((BB * NCH * DIN) / 256), dim3(256), 0, stream>>>(
        delta, xc_bf, xz_bf, x_dbl, A_log, D_skip, PQ, y_bf);
    // 11. out_proj (bf16 MFMA, TN=64) + fused residual/gate epilogue -> out
    k_mfma2<64, 2><<<dim3(D_MODEL / 64, NTOK / 128), dim3(256), 0, stream>>>(
        y_bf, w_out_bf, out, D_MODEL, DIN, x, mod);
}